// Round 7
// baseline (104.983 us; speedup 1.0000x reference)
//
#include <hip/hip_runtime.h>
#include <hip/hip_bf16.h>
#include <math.h>

#define DIMX 1024
#define SEQ  1024
#define HD   64
#define QH   2
#define TH   14
#define QKVN 2688   // 3*896
#define LN_EPS 1e-5f
#define NSPLIT 4

typedef __bf16 bf16x8 __attribute__((ext_vector_type(8)));
typedef float  f32x4  __attribute__((ext_vector_type(4)));
typedef unsigned short u16x8 __attribute__((ext_vector_type(8)));

__device__ inline unsigned short f2b_rne(float f) {
  unsigned int u = __float_as_uint(f);
  unsigned int r = (u + 0x7FFF + ((u >> 16) & 1)) >> 16;
  return (unsigned short)r;
}

__device__ inline float waveRedSum(float v) {
  #pragma unroll
  for (int off = 32; off; off >>= 1) v += __shfl_xor(v, off, 64);
  return v;
}

// ---------------- fused f32 -> bf16 convert for x, Wq|Wk|Wv, Wo ----------------
__global__ __launch_bounds__(256) void k_f2b_all(
    const float* __restrict__ x, const float* __restrict__ wq,
    const float* __restrict__ wk, const float* __restrict__ wv,
    const float* __restrict__ wo,
    unsigned short* __restrict__ x_bf, unsigned short* __restrict__ wqkv_bf,
    unsigned short* __restrict__ wo_bf) {
  long i = ((long)blockIdx.x * 256 + threadIdx.x) * 4;
  float4 v;
  unsigned short* dst;
  if (i < 1048576) {
    v = *reinterpret_cast<const float4*>(x + i);
    dst = x_bf + i;
  } else if (i < 3801088) {
    long j = i - 1048576;
    const float* s = (j < 917504) ? wq + j
                   : (j < 1835008) ? wk + (j - 917504)
                                   : wv + (j - 1835008);
    v = *reinterpret_cast<const float4*>(s);
    dst = wqkv_bf + j;
  } else {
    long j = i - 3801088;
    v = *reinterpret_cast<const float4*>(wo + j);
    dst = wo_bf + j;
  }
  ushort4 o;
  o.x = f2b_rne(v.x); o.y = f2b_rne(v.y); o.z = f2b_rne(v.z); o.w = f2b_rne(v.w);
  *reinterpret_cast<ushort4*>(dst) = o;
}

// ---------------- quantum prep ----------------
__global__ __launch_bounds__(128) void k_qprep(
    const float* __restrict__ x, const float* __restrict__ qsW,
    const float* __restrict__ qsb, const float* __restrict__ lng,
    const float* __restrict__ lnb, const float* __restrict__ qfreq,
    const float* __restrict__ qshift,
    unsigned short* __restrict__ qcs, unsigned short* __restrict__ kcs) {
  int b = blockIdx.x; int h = b >> 10; int i = b & 1023;
  int o = threadIdx.x;  // 0..127
  __shared__ float xrow[HD];
  __shared__ float red[4];
  __shared__ float qsv[128];
  if (o < HD) xrow[o] = x[i * DIMX + h * HD + o];
  __syncthreads();
  float s = qsb[o];
  #pragma unroll
  for (int d = 0; d < HD; d += 4) {
    float4 w = *reinterpret_cast<const float4*>(qsW + o * HD + d);
    float4 xv = *reinterpret_cast<const float4*>(&xrow[d]);
    s += xv.x * w.x + xv.y * w.y + xv.z * w.z + xv.w * w.w;
  }
  int wid = o >> 6, lane = o & 63;
  float ws = waveRedSum(s);
  if (lane == 0) red[wid] = ws;
  __syncthreads();
  float mu = (red[0] + red[1]) * (1.0f / 128.0f);
  float dv = s - mu;
  float ws2 = waveRedSum(dv * dv);
  if (lane == 0) red[2 + wid] = ws2;
  __syncthreads();
  float var = (red[2] + red[3]) * (1.0f / 128.0f);
  float y = dv * rsqrtf(var + LN_EPS) * lng[o] + lnb[o];
  qsv[o] = tanhf(y);
  __syncthreads();
  float freq = qfreq[h], shift = qshift[h];
  size_t base = ((size_t)h * 1024 + i) * 128;
  if (o < HD) {
    float amp = qsv[o];
    float a = qsv[64 + o] * freq + shift;
    float sn, cs;
    __sincosf(a, &sn, &cs);
    qcs[base + o]      = f2b_rne(amp * cs);
    qcs[base + 64 + o] = f2b_rne(amp * sn);
  } else {
    int d = o - 64;
    float amp = qsv[d];
    float bAng = qsv[64 + d] * freq;
    float sn, cs;
    __sincosf(bAng, &sn, &cs);
    kcs[base + d]      = f2b_rne(amp * cs);
    kcs[base + 64 + d] = f2b_rne(amp * sn);
  }
}

// ---------------- 64-col block transpose: src[kv][col0+h*64+d] -> dst[h][d][kv] ----------------
__global__ __launch_bounds__(256) void k_tr64(const unsigned short* __restrict__ src, int ld,
                                              int col0, unsigned short* __restrict__ dst) {
  int h = blockIdx.y, kv0 = blockIdx.x * 64;
  int t = threadIdx.x;
  __shared__ unsigned short tile[64][72];
  #pragma unroll
  for (int pass = 0; pass < 2; ++pass) {
    int s = pass * 256 + t;
    int r = s >> 3, c8 = (s & 7) * 8;
    u16x8 v = *reinterpret_cast<const u16x8*>(src + (size_t)(kv0 + r) * ld + col0 + h * 64 + c8);
    *reinterpret_cast<u16x8*>(&tile[r][c8]) = v;
  }
  __syncthreads();
  #pragma unroll
  for (int pass = 0; pass < 2; ++pass) {
    int s = pass * 256 + t;
    int d = s >> 3, k8 = (s & 7) * 8;
    u16x8 o;
    #pragma unroll
    for (int j = 0; j < 8; ++j) o[j] = tile[k8 + j][d];
    *reinterpret_cast<u16x8*>(dst + (size_t)h * 65536 + (size_t)d * 1024 + kv0 + k8) = o;
  }
}

// ---------------- fused flash attention, kv-split ----------------
template <int DQK>
__global__ __launch_bounds__(256) void k_fattn(
    const unsigned short* __restrict__ Qb, long q_hstep, int ldq,
    const unsigned short* __restrict__ Kb, long k_hstep, int ldk,
    const unsigned short* __restrict__ Vtb, long v_hstep, int lh0,
    float* __restrict__ pout, float* __restrict__ pml) {
  const int LQ = DQK + 8;
  const int KREG = DQK / 32;
  __shared__ unsigned short Qs[64 * LQ];
  __shared__ unsigned short Ks[2][64 * LQ];
  __shared__ unsigned short Vs[2][64 * 72];
  __shared__ unsigned short Ps[64 * 72];
  int h = blockIdx.y;
  int q0 = blockIdx.x * 64;
  int split = blockIdx.z;
  int kv0 = split * 256;
  int t = threadIdx.x, lane = t & 63, w = t >> 6;
  int g = lane >> 4, li = lane & 15;
  const unsigned short* Qp = Qb + (size_t)h * q_hstep;
  const unsigned short* Kp = Kb + (size_t)h * k_hstep;
  const unsigned short* Vp = Vtb + (size_t)h * v_hstep;

  #pragma unroll
  for (int i = 0; i < DQK / 32; ++i) {
    int s = i * 64 + lane;
    int r = s / (DQK / 8), c8 = (s % (DQK / 8)) * 8;
    u16x8 v = *reinterpret_cast<const u16x8*>(Qp + (size_t)(q0 + w * 16 + r) * ldq + c8);
    *reinterpret_cast<u16x8*>(&Qs[(w * 16 + r) * LQ + c8]) = v;
  }

  u16x8 kreg[KREG], vreg[2];
  auto loadKV = [&](int tile) {
    int j0 = kv0 + tile * 64;
    #pragma unroll
    for (int i = 0; i < KREG; ++i) {
      int s = i * 256 + t;
      int r = s / (DQK / 8), c8 = (s % (DQK / 8)) * 8;
      kreg[i] = *reinterpret_cast<const u16x8*>(Kp + (size_t)(j0 + r) * ldk + c8);
    }
    #pragma unroll
    for (int i = 0; i < 2; ++i) {
      int s = i * 256 + t;
      int d = s >> 3, c8 = (s & 7) * 8;
      vreg[i] = *reinterpret_cast<const u16x8*>(Vp + (size_t)d * 1024 + j0 + c8);
    }
  };
  auto writeKV = [&](int buf) {
    #pragma unroll
    for (int i = 0; i < KREG; ++i) {
      int s = i * 256 + t;
      int r = s / (DQK / 8), c8 = (s % (DQK / 8)) * 8;
      *reinterpret_cast<u16x8*>(&Ks[buf][r * LQ + c8]) = kreg[i];
    }
    #pragma unroll
    for (int i = 0; i < 2; ++i) {
      int s = i * 256 + t;
      int d = s >> 3, c8 = (s & 7) * 8;
      *reinterpret_cast<u16x8*>(&Vs[buf][d * 72 + c8]) = vreg[i];
    }
  };

  loadKV(0);
  writeKV(0);
  loadKV(1);
  __syncthreads();

  f32x4 acc_o[4] = {};
  float mrow[4] = {-1e30f, -1e30f, -1e30f, -1e30f};
  float lrow[4] = {0.f, 0.f, 0.f, 0.f};

  #pragma unroll
  for (int tile = 0; tile < 4; ++tile) {
    int cur = tile & 1;
    if (tile < 3) writeKV(cur ^ 1);
    if (tile < 2) loadKV(tile + 2);
    f32x4 s_acc[4] = {};
    #pragma unroll
    for (int kk = 0; kk < DQK / 32; ++kk) {
      bf16x8 aq = *reinterpret_cast<const bf16x8*>(&Qs[(w * 16 + li) * LQ + kk * 32 + g * 8]);
      #pragma unroll
      for (int n = 0; n < 4; ++n) {
        bf16x8 bk = *reinterpret_cast<const bf16x8*>(&Ks[cur][(n * 16 + li) * LQ + kk * 32 + g * 8]);
        s_acc[n] = __builtin_amdgcn_mfma_f32_16x16x32_bf16(aq, bk, s_acc[n], 0, 0, 0);
      }
    }
    #pragma unroll
    for (int r = 0; r < 4; ++r) {
      float tm = fmaxf(fmaxf(s_acc[0][r], s_acc[1][r]), fmaxf(s_acc[2][r], s_acc[3][r]));
      #pragma unroll
      for (int m = 1; m < 16; m <<= 1) tm = fmaxf(tm, __shfl_xor(tm, m, 64));
      float mn = fmaxf(mrow[r], tm);
      float sf = __expf((mrow[r] - mn) * 0.125f);
      mrow[r] = mn;
      lrow[r] *= sf;
      #pragma unroll
      for (int n = 0; n < 4; ++n) acc_o[n][r] *= sf;
      float rs = 0.f;
      #pragma unroll
      for (int n = 0; n < 4; ++n) {
        float p = __expf((s_acc[n][r] - mn) * 0.125f);
        s_acc[n][r] = p;
        rs += p;
      }
      #pragma unroll
      for (int m = 1; m < 16; m <<= 1) rs += __shfl_xor(rs, m, 64);
      lrow[r] += rs;
    }
    #pragma unroll
    for (int n = 0; n < 4; ++n)
      #pragma unroll
      for (int r = 0; r < 4; ++r)
        Ps[(w * 16 + g * 4 + r) * 72 + n * 16 + li] = f2b_rne(s_acc[n][r]);
    #pragma unroll
    for (int kk = 0; kk < 2; ++kk) {
      bf16x8 ap = *reinterpret_cast<const bf16x8*>(&Ps[(w * 16 + li) * 72 + kk * 32 + g * 8]);
      #pragma unroll
      for (int n = 0; n < 4; ++n) {
        bf16x8 bv = *reinterpret_cast<const bf16x8*>(&Vs[cur][(n * 16 + li) * 72 + kk * 32 + g * 8]);
        acc_o[n] = __builtin_amdgcn_mfma_f32_16x16x32_bf16(ap, bv, acc_o[n], 0, 0, 0);
      }
    }
    __syncthreads();
  }

  size_t rowbase = (size_t)((lh0 + h) * NSPLIT + split) * 1024;
  #pragma unroll
  for (int r = 0; r < 4; ++r) {
    int qr = q0 + w * 16 + g * 4 + r;
    #pragma unroll
    for (int n = 0; n < 4; ++n)
      pout[(rowbase + qr) * 64 + n * 16 + li] = acc_o[n][r];
    if (li == 0) {
      pml[(rowbase + qr) * 2 + 0] = mrow[r];
      pml[(rowbase + qr) * 2 + 1] = lrow[r];
    }
  }
}

// ---------------- merge kv-split partials -> concat bf16 ----------------
__global__ __launch_bounds__(256) void k_fmerge(
    const float* __restrict__ pout, const float* __restrict__ pml,
    unsigned short* __restrict__ concat) {
  int rq = blockIdx.x * 4 + (threadIdx.x >> 6);
  int lh = rq >> 10, q = rq & 1023;
  int d = threadIdx.x & 63;
  float m_s[NSPLIT], l_s[NSPLIT];
  float M = -1e30f;
  #pragma unroll
  for (int s = 0; s < NSPLIT; ++s) {
    size_t rb = (size_t)(lh * NSPLIT + s) * 1024 + q;
    m_s[s] = pml[rb * 2 + 0];
    l_s[s] = pml[rb * 2 + 1];
    M = fmaxf(M, m_s[s]);
  }
  float num = 0.f, den = 0.f;
  #pragma unroll
  for (int s = 0; s < NSPLIT; ++s) {
    float wgt = __expf((m_s[s] - M) * 0.125f);
    num += wgt * pout[((size_t)(lh * NSPLIT + s) * 1024 + q) * 64 + d];
    den += wgt * l_s[s];
  }
  concat[(size_t)q * DIMX + lh * 64 + d] = f2b_rne(num / den);
}

// ---------------- 128x128 bf16 MFMA GEMM (m97-style): C = A * B^T (+bias) ----------------
// global_load_lds width=16 staging, linear LDS [128][64], 4 waves, 4x4 acc/wave.
template <int HAS_BIAS, int BF16_OUT>
__global__ __launch_bounds__(256) void k_gemm128(
    const unsigned short* __restrict__ A, const unsigned short* __restrict__ B,
    void* __restrict__ Cv, const float* __restrict__ bias,
    int K, int lda, int ldb, int ldc) {
  __shared__ unsigned short As[128 * 64];
  __shared__ unsigned short Bs[128 * 64];
  int t = threadIdx.x, lane = t & 63, w = t >> 6;
  int wr = w >> 1, wc = w & 1;
  int g = lane >> 4, li = lane & 15;
  int mb = blockIdx.y * 128, nb = blockIdx.x * 128;
  int rstg = t >> 3;          // 0..31 (row within 32-row issue chunk)
  int cstg = (t & 7) * 8;     // col element
  f32x4 acc[4][4] = {};
  for (int kb = 0; kb < K; kb += 64) {
    __syncthreads();          // previous MFMA reads complete before overwrite
    #pragma unroll
    for (int i = 0; i < 4; ++i) {
      __builtin_amdgcn_global_load_lds(
          (const __attribute__((address_space(1))) unsigned int*)(A + (size_t)(mb + i * 32 + rstg) * lda + kb + cstg),
          (__attribute__((address_space(3))) unsigned int*)(As + (i * 256 + t) * 8),
          16, 0, 0);
      __builtin_amdgcn_global_load_lds(
          (const __attribute__((address_space(1))) unsigned int*)(B + (size_t)(nb + i * 32 + rstg) * ldb + kb + cstg),
          (__attribute__((address_space(3))) unsigned int*)(Bs + (i * 256 + t) * 8),
          16, 0, 0);
    }
    __syncthreads();          // drains vmcnt -> staged data visible
    #pragma unroll
    for (int kk = 0; kk < 2; ++kk) {
      bf16x8 af[4], bfr[4];
      #pragma unroll
      for (int m = 0; m < 4; ++m)
        af[m] = *reinterpret_cast<const bf16x8*>(&As[(wr * 64 + m * 16 + li) * 64 + kk * 32 + g * 8]);
      #pragma unroll
      for (int n = 0; n < 4; ++n)
        bfr[n] = *reinterpret_cast<const bf16x8*>(&Bs[(wc * 64 + n * 16 + li) * 64 + kk * 32 + g * 8]);
      #pragma unroll
      for (int m = 0; m < 4; ++m)
        #pragma unroll
        for (int n = 0; n < 4; ++n)
          acc[m][n] = __builtin_amdgcn_mfma_f32_16x16x32_bf16(af[m], bfr[n], acc[m][n], 0, 0, 0);
    }
  }
  #pragma unroll
  for (int m = 0; m < 4; ++m) {
    int row0 = mb + wr * 64 + m * 16 + g * 4;
    #pragma unroll
    for (int n = 0; n < 4; ++n) {
      int col = nb + wc * 64 + n * 16 + li;
      float bval = HAS_BIAS ? bias[col] : 0.0f;
      #pragma unroll
      for (int r = 0; r < 4; ++r) {
        size_t idx = (size_t)(row0 + r) * ldc + col;
        if (BF16_OUT) ((unsigned short*)Cv)[idx] = f2b_rne(acc[m][n][r] + bval);
        else          ((float*)Cv)[idx] = acc[m][n][r] + bval;
      }
    }
  }
}

extern "C" void kernel_launch(void* const* d_in, const int* in_sizes, int n_in,
                              void* d_out, int out_size, void* d_ws, size_t ws_size,
                              hipStream_t stream) {
  const float* x      = (const float*)d_in[0];
  const float* qsW    = (const float*)d_in[1];
  const float* qsb    = (const float*)d_in[2];
  const float* lng    = (const float*)d_in[3];
  const float* lnb    = (const float*)d_in[4];
  const float* qfreq  = (const float*)d_in[5];
  const float* qshift = (const float*)d_in[6];
  const float* Wq     = (const float*)d_in[7];
  const float* Wk     = (const float*)d_in[8];
  const float* Wv     = (const float*)d_in[9];
  const float* Wo     = (const float*)d_in[10];
  const float* bo     = (const float*)d_in[11];
  float* out = (float*)d_out;

  char* ws = (char*)d_ws;
  size_t off = 0;
  auto alloc = [&](size_t bytes) { char* p = ws + off; off += (bytes + 255) & ~(size_t)255; return p; };
  unsigned short* x_bf      = (unsigned short*)alloc((size_t)SEQ * DIMX * 2);
  unsigned short* wqkv_bf   = (unsigned short*)alloc((size_t)QKVN * DIMX * 2);
  unsigned short* wo_bf     = (unsigned short*)alloc((size_t)DIMX * DIMX * 2);
  unsigned short* concat_bf = (unsigned short*)alloc((size_t)SEQ * DIMX * 2);
  unsigned short* qkv_bf    = (unsigned short*)alloc((size_t)SEQ * QKVN * 2);
  unsigned short* qcs       = (unsigned short*)alloc((size_t)QH * SEQ * 128 * 2);
  unsigned short* kcs       = (unsigned short*)alloc((size_t)QH * SEQ * 128 * 2);
  unsigned short* vt        = (unsigned short*)alloc((size_t)TH * HD * SEQ * 2);
  unsigned short* xt        = (unsigned short*)alloc((size_t)QH * HD * SEQ * 2);
  float*          pout      = (float*)alloc((size_t)16 * NSPLIT * SEQ * 64 * 4);
  float*          pml       = (float*)alloc((size_t)16 * NSPLIT * SEQ * 2 * 4);

  k_f2b_all<<<4736, 256, 0, stream>>>(x, Wq, Wk, Wv, Wo, x_bf, wqkv_bf, wo_bf);
  k_qprep<<<QH * SEQ, 128, 0, stream>>>(x, qsW, qsb, lng, lnb, qfreq, qshift, qcs, kcs);

  // QKV projection -> bf16 qkv  (M=1024, N=2688, K=1024)
  k_gemm128<0, 1><<<dim3(QKVN / 128, SEQ / 128), 256, 0, stream>>>(
      x_bf, wqkv_bf, qkv_bf, nullptr, DIMX, DIMX, DIMX, QKVN);

  k_tr64<<<dim3(16, TH), 256, 0, stream>>>(qkv_bf, QKVN, 1792, vt);
  k_tr64<<<dim3(16, QH), 256, 0, stream>>>(x_bf, DIMX, 0, xt);

  // fused attention, kv-split: quantum heads lh 0..1 (DQK=128, V=x), trad lh 2..15
  k_fattn<128><<<dim3(16, QH, NSPLIT), 256, 0, stream>>>(
      qcs, (long)SEQ * 128, 128, kcs, (long)SEQ * 128, 128, xt, (long)HD * SEQ, 0, pout, pml);
  k_fattn<64><<<dim3(16, TH, NSPLIT), 256, 0, stream>>>(
      qkv_bf, 64, QKVN, qkv_bf + 896, 64, QKVN, vt, (long)HD * SEQ, 2, pout, pml);
  k_fmerge<<<16 * SEQ / 4, 256, 0, stream>>>(pout, pml, concat_bf);

  // output projection (M=1024, N=1024, K=1024) + bias
  k_gemm128<1, 0><<<dim3(DIMX / 128, SEQ / 128), 256, 0, stream>>>(
      concat_bf, wo_bf, out, bo, DIMX, DIMX, DIMX, DIMX);
}

// Round 8
// 81.528 us; speedup vs baseline: 1.2877x; 1.2877x over previous
//
#include <hip/hip_runtime.h>
#include <hip/hip_bf16.h>
#include <math.h>

#define DIMX 1024
#define SEQ  1024
#define HD   64
#define QH   2
#define TH   14
#define QKVN 2688   // 3*896
#define LN_EPS 1e-5f

typedef __bf16 bf16x8 __attribute__((ext_vector_type(8)));
typedef float  f32x4  __attribute__((ext_vector_type(4)));
typedef unsigned short u16x8 __attribute__((ext_vector_type(8)));

__device__ inline unsigned short f2b_rne(float f) {
  unsigned int u = __float_as_uint(f);
  unsigned int r = (u + 0x7FFF + ((u >> 16) & 1)) >> 16;
  return (unsigned short)r;
}

__device__ inline float waveRedSum(float v) {
  #pragma unroll
  for (int off = 32; off; off >>= 1) v += __shfl_xor(v, off, 64);
  return v;
}

// ---------------- fused f32 -> bf16 convert for x, Wq|Wk|Wv, Wo ----------------
__global__ __launch_bounds__(256) void k_f2b_all(
    const float* __restrict__ x, const float* __restrict__ wq,
    const float* __restrict__ wk, const float* __restrict__ wv,
    const float* __restrict__ wo,
    unsigned short* __restrict__ x_bf, unsigned short* __restrict__ wqkv_bf,
    unsigned short* __restrict__ wo_bf) {
  long i = ((long)blockIdx.x * 256 + threadIdx.x) * 4;
  float4 v;
  unsigned short* dst;
  if (i < 1048576) {
    v = *reinterpret_cast<const float4*>(x + i);
    dst = x_bf + i;
  } else if (i < 3801088) {
    long j = i - 1048576;
    const float* s = (j < 917504) ? wq + j
                   : (j < 1835008) ? wk + (j - 917504)
                                   : wv + (j - 1835008);
    v = *reinterpret_cast<const float4*>(s);
    dst = wqkv_bf + j;
  } else {
    long j = i - 3801088;
    v = *reinterpret_cast<const float4*>(wo + j);
    dst = wo_bf + j;
  }
  ushort4 o;
  o.x = f2b_rne(v.x); o.y = f2b_rne(v.y); o.z = f2b_rne(v.z); o.w = f2b_rne(v.w);
  *reinterpret_cast<ushort4*>(dst) = o;
}

// ---------------- quantum prep ----------------
__global__ __launch_bounds__(128) void k_qprep(
    const float* __restrict__ x, const float* __restrict__ qsW,
    const float* __restrict__ qsb, const float* __restrict__ lng,
    const float* __restrict__ lnb, const float* __restrict__ qfreq,
    const float* __restrict__ qshift,
    unsigned short* __restrict__ qcs, unsigned short* __restrict__ kcs) {
  int b = blockIdx.x; int h = b >> 10; int i = b & 1023;
  int o = threadIdx.x;  // 0..127
  __shared__ float xrow[HD];
  __shared__ float red[4];
  __shared__ float qsv[128];
  if (o < HD) xrow[o] = x[i * DIMX + h * HD + o];
  __syncthreads();
  float s = qsb[o];
  #pragma unroll
  for (int d = 0; d < HD; d += 4) {
    float4 w = *reinterpret_cast<const float4*>(qsW + o * HD + d);
    float4 xv = *reinterpret_cast<const float4*>(&xrow[d]);
    s += xv.x * w.x + xv.y * w.y + xv.z * w.z + xv.w * w.w;
  }
  int wid = o >> 6, lane = o & 63;
  float ws = waveRedSum(s);
  if (lane == 0) red[wid] = ws;
  __syncthreads();
  float mu = (red[0] + red[1]) * (1.0f / 128.0f);
  float dv = s - mu;
  float ws2 = waveRedSum(dv * dv);
  if (lane == 0) red[2 + wid] = ws2;
  __syncthreads();
  float var = (red[2] + red[3]) * (1.0f / 128.0f);
  float y = dv * rsqrtf(var + LN_EPS) * lng[o] + lnb[o];
  qsv[o] = tanhf(y);
  __syncthreads();
  float freq = qfreq[h], shift = qshift[h];
  size_t base = ((size_t)h * 1024 + i) * 128;
  if (o < HD) {
    float amp = qsv[o];
    float a = qsv[64 + o] * freq + shift;
    float sn, cs;
    __sincosf(a, &sn, &cs);
    qcs[base + o]      = f2b_rne(amp * cs);
    qcs[base + 64 + o] = f2b_rne(amp * sn);
  } else {
    int d = o - 64;
    float amp = qsv[d];
    float bAng = qsv[64 + d] * freq;
    float sn, cs;
    __sincosf(bAng, &sn, &cs);
    kcs[base + d]      = f2b_rne(amp * cs);
    kcs[base + 64 + d] = f2b_rne(amp * sn);
  }
}

// ---------------- combined 64-col transposes: V (heads 0..13) and x (heads 14..15) ----------------
__global__ __launch_bounds__(256) void k_tr64all(
    const unsigned short* __restrict__ qkv, const unsigned short* __restrict__ xb,
    unsigned short* __restrict__ vt, unsigned short* __restrict__ xt) {
  int hy = blockIdx.y, kv0 = blockIdx.x * 64;
  const unsigned short* src;
  unsigned short* dst;
  int ld, col0;
  if (hy < TH) { src = qkv; ld = QKVN; col0 = 1792 + hy * 64; dst = vt + (size_t)hy * 65536; }
  else         { src = xb;  ld = DIMX; col0 = (hy - TH) * 64; dst = xt + (size_t)(hy - TH) * 65536; }
  int t = threadIdx.x;
  __shared__ unsigned short tile[64][72];
  #pragma unroll
  for (int pass = 0; pass < 2; ++pass) {
    int s = pass * 256 + t;
    int r = s >> 3, c8 = (s & 7) * 8;
    u16x8 v = *reinterpret_cast<const u16x8*>(src + (size_t)(kv0 + r) * ld + col0 + c8);
    *reinterpret_cast<u16x8*>(&tile[r][c8]) = v;
  }
  __syncthreads();
  #pragma unroll
  for (int pass = 0; pass < 2; ++pass) {
    int s = pass * 256 + t;
    int d = s >> 3, k8 = (s & 7) * 8;
    u16x8 o;
    #pragma unroll
    for (int j = 0; j < 8; ++j) o[j] = tile[k8 + j][d];
    *reinterpret_cast<u16x8*>(dst + (size_t)d * 1024 + kv0 + k8) = o;
  }
}

// ---------------- fused flash attention, kv-split ----------------
// NT kv-tiles of 64 per block. Partial slot = slot0 + h*gridDim.z + split.
template <int DQK, int NT>
__global__ __launch_bounds__(256) void k_fattn(
    const unsigned short* __restrict__ Qb, long q_hstep, int ldq,
    const unsigned short* __restrict__ Kb, long k_hstep, int ldk,
    const unsigned short* __restrict__ Vtb, long v_hstep, int slot0,
    float* __restrict__ pout, float* __restrict__ pml) {
  const int LQ = DQK + 8;
  const int KREG = DQK / 32;
  __shared__ unsigned short Qs[64 * LQ];
  __shared__ unsigned short Ks[2][64 * LQ];
  __shared__ unsigned short Vs[2][64 * 72];
  __shared__ unsigned short Ps[64 * 72];
  int h = blockIdx.y;
  int q0 = blockIdx.x * 64;
  int split = blockIdx.z;
  int kv0 = split * (NT * 64);
  int t = threadIdx.x, lane = t & 63, w = t >> 6;
  int g = lane >> 4, li = lane & 15;
  const unsigned short* Qp = Qb + (size_t)h * q_hstep;
  const unsigned short* Kp = Kb + (size_t)h * k_hstep;
  const unsigned short* Vp = Vtb + (size_t)h * v_hstep;

  #pragma unroll
  for (int i = 0; i < DQK / 32; ++i) {
    int s = i * 64 + lane;
    int r = s / (DQK / 8), c8 = (s % (DQK / 8)) * 8;
    u16x8 v = *reinterpret_cast<const u16x8*>(Qp + (size_t)(q0 + w * 16 + r) * ldq + c8);
    *reinterpret_cast<u16x8*>(&Qs[(w * 16 + r) * LQ + c8]) = v;
  }

  u16x8 kreg[KREG], vreg[2];
  auto loadKV = [&](int tile) {
    int j0 = kv0 + tile * 64;
    #pragma unroll
    for (int i = 0; i < KREG; ++i) {
      int s = i * 256 + t;
      int r = s / (DQK / 8), c8 = (s % (DQK / 8)) * 8;
      kreg[i] = *reinterpret_cast<const u16x8*>(Kp + (size_t)(j0 + r) * ldk + c8);
    }
    #pragma unroll
    for (int i = 0; i < 2; ++i) {
      int s = i * 256 + t;
      int d = s >> 3, c8 = (s & 7) * 8;
      vreg[i] = *reinterpret_cast<const u16x8*>(Vp + (size_t)d * 1024 + j0 + c8);
    }
  };
  auto writeKV = [&](int buf) {
    #pragma unroll
    for (int i = 0; i < KREG; ++i) {
      int s = i * 256 + t;
      int r = s / (DQK / 8), c8 = (s % (DQK / 8)) * 8;
      *reinterpret_cast<u16x8*>(&Ks[buf][r * LQ + c8]) = kreg[i];
    }
    #pragma unroll
    for (int i = 0; i < 2; ++i) {
      int s = i * 256 + t;
      int d = s >> 3, c8 = (s & 7) * 8;
      *reinterpret_cast<u16x8*>(&Vs[buf][d * 72 + c8]) = vreg[i];
    }
  };

  loadKV(0);
  writeKV(0);
  loadKV(1);
  __syncthreads();

  f32x4 acc_o[4] = {};
  float mrow[4] = {-1e30f, -1e30f, -1e30f, -1e30f};
  float lrow[4] = {0.f, 0.f, 0.f, 0.f};

  #pragma unroll
  for (int tile = 0; tile < NT; ++tile) {
    int cur = tile & 1;
    if (tile < NT - 1) writeKV(cur ^ 1);
    if (tile < NT - 2) loadKV(tile + 2);
    f32x4 s_acc[4] = {};
    #pragma unroll
    for (int kk = 0; kk < DQK / 32; ++kk) {
      bf16x8 aq = *reinterpret_cast<const bf16x8*>(&Qs[(w * 16 + li) * LQ + kk * 32 + g * 8]);
      #pragma unroll
      for (int n = 0; n < 4; ++n) {
        bf16x8 bk = *reinterpret_cast<const bf16x8*>(&Ks[cur][(n * 16 + li) * LQ + kk * 32 + g * 8]);
        s_acc[n] = __builtin_amdgcn_mfma_f32_16x16x32_bf16(aq, bk, s_acc[n], 0, 0, 0);
      }
    }
    #pragma unroll
    for (int r = 0; r < 4; ++r) {
      float tm = fmaxf(fmaxf(s_acc[0][r], s_acc[1][r]), fmaxf(s_acc[2][r], s_acc[3][r]));
      #pragma unroll
      for (int m = 1; m < 16; m <<= 1) tm = fmaxf(tm, __shfl_xor(tm, m, 64));
      float mn = fmaxf(mrow[r], tm);
      float sf = __expf((mrow[r] - mn) * 0.125f);
      mrow[r] = mn;
      lrow[r] *= sf;
      #pragma unroll
      for (int n = 0; n < 4; ++n) acc_o[n][r] *= sf;
      float rs = 0.f;
      #pragma unroll
      for (int n = 0; n < 4; ++n) {
        float p = __expf((s_acc[n][r] - mn) * 0.125f);
        s_acc[n][r] = p;
        rs += p;
      }
      #pragma unroll
      for (int m = 1; m < 16; m <<= 1) rs += __shfl_xor(rs, m, 64);
      lrow[r] += rs;
    }
    #pragma unroll
    for (int n = 0; n < 4; ++n)
      #pragma unroll
      for (int r = 0; r < 4; ++r)
        Ps[(w * 16 + g * 4 + r) * 72 + n * 16 + li] = f2b_rne(s_acc[n][r]);
    #pragma unroll
    for (int kk = 0; kk < 2; ++kk) {
      bf16x8 ap = *reinterpret_cast<const bf16x8*>(&Ps[(w * 16 + li) * 72 + kk * 32 + g * 8]);
      #pragma unroll
      for (int n = 0; n < 4; ++n) {
        bf16x8 bv = *reinterpret_cast<const bf16x8*>(&Vs[cur][(n * 16 + li) * 72 + kk * 32 + g * 8]);
        acc_o[n] = __builtin_amdgcn_mfma_f32_16x16x32_bf16(ap, bv, acc_o[n], 0, 0, 0);
      }
    }
    __syncthreads();
  }

  size_t rowbase = (size_t)(slot0 + h * gridDim.z + split) * 1024;
  #pragma unroll
  for (int r = 0; r < 4; ++r) {
    int qr = q0 + w * 16 + g * 4 + r;
    #pragma unroll
    for (int n = 0; n < 4; ++n)
      pout[(rowbase + qr) * 64 + n * 16 + li] = acc_o[n][r];
    if (li == 0) {
      pml[(rowbase + qr) * 2 + 0] = mrow[r];
      pml[(rowbase + qr) * 2 + 1] = lrow[r];
    }
  }
}

// ---------------- merge kv-split partials -> concat bf16 ----------------
// Slots: quantum lh 0..1 -> 8 splits at lh*8; trad lh 2..15 -> 4 splits at 16+(lh-2)*4.
__global__ __launch_bounds__(256) void k_fmerge(
    const float* __restrict__ pout, const float* __restrict__ pml,
    unsigned short* __restrict__ concat) {
  int rq = blockIdx.x * 4 + (threadIdx.x >> 6);
  int lh = rq >> 10, q = rq & 1023;
  int d = threadIdx.x & 63;
  int s0 = (lh < 2) ? lh * 8 : 16 + (lh - 2) * 4;
  int ns = (lh < 2) ? 8 : 4;
  float m_s[8], l_s[8];
  float M = -1e30f;
  #pragma unroll
  for (int s = 0; s < 8; ++s) {
    if (s < ns) {
      size_t rb = (size_t)(s0 + s) * 1024 + q;
      m_s[s] = pml[rb * 2 + 0];
      l_s[s] = pml[rb * 2 + 1];
      M = fmaxf(M, m_s[s]);
    }
  }
  float num = 0.f, den = 0.f;
  #pragma unroll
  for (int s = 0; s < 8; ++s) {
    if (s < ns) {
      float wgt = __expf((m_s[s] - M) * 0.125f);
      num += wgt * pout[((size_t)(s0 + s) * 1024 + q) * 64 + d];
      den += wgt * l_s[s];
    }
  }
  concat[(size_t)q * DIMX + lh * 64 + d] = f2b_rne(num / den);
}

// ---------------- 64x64 bf16 MFMA GEMM: global_load_lds + XOR-swizzle (rule 21) ------
// Linear LDS [64][64]; global source colblock pre-swizzled by row&7; reads apply the
// same XOR. C = A * B^T (+bias).
template <int HAS_BIAS, int BF16_OUT>
__global__ __launch_bounds__(256) void k_gemm64s(
    const unsigned short* __restrict__ A, const unsigned short* __restrict__ B,
    void* __restrict__ Cv, const float* __restrict__ bias,
    int K, int lda, int ldb, int ldc) {
  __shared__ unsigned short As[64 * 64];
  __shared__ unsigned short Bs[64 * 64];
  int t = threadIdx.x, lane = t & 63, w = t >> 6;
  int wr = w >> 1, wc = w & 1;
  int g = lane >> 4, li = lane & 15;
  int mb = blockIdx.y * 64, nb = blockIdx.x * 64;
  int rstg = t >> 3;                          // 0..31
  int cswz = (((t & 7) ^ (rstg & 7)) * 8);    // pre-swizzled global colblock (elements)
  f32x4 acc[2][2] = {};
  for (int kb = 0; kb < K; kb += 64) {
    __syncthreads();            // prior MFMA ds_reads done before overwrite
    #pragma unroll
    for (int i = 0; i < 2; ++i) {
      __builtin_amdgcn_global_load_lds(
          (const __attribute__((address_space(1))) unsigned int*)(A + (size_t)(mb + i * 32 + rstg) * lda + kb + cswz),
          (__attribute__((address_space(3))) unsigned int*)(As + i * 2048 + t * 8), 16, 0, 0);
      __builtin_amdgcn_global_load_lds(
          (const __attribute__((address_space(1))) unsigned int*)(B + (size_t)(nb + i * 32 + rstg) * ldb + kb + cswz),
          (__attribute__((address_space(3))) unsigned int*)(Bs + i * 2048 + t * 8), 16, 0, 0);
    }
    __syncthreads();            // vmcnt drained -> staged data visible
    #pragma unroll
    for (int kk = 0; kk < 2; ++kk) {
      bf16x8 af[2], bfr[2];
      #pragma unroll
      for (int m = 0; m < 2; ++m) {
        int r = wr * 32 + m * 16 + li;
        int cb = kk * 4 + g;
        af[m] = *reinterpret_cast<const bf16x8*>(&As[r * 64 + ((cb ^ (r & 7)) * 8)]);
      }
      #pragma unroll
      for (int n = 0; n < 2; ++n) {
        int r = wc * 32 + n * 16 + li;
        int cb = kk * 4 + g;
        bfr[n] = *reinterpret_cast<const bf16x8*>(&Bs[r * 64 + ((cb ^ (r & 7)) * 8)]);
      }
      #pragma unroll
      for (int m = 0; m < 2; ++m)
        #pragma unroll
        for (int n = 0; n < 2; ++n)
          acc[m][n] = __builtin_amdgcn_mfma_f32_16x16x32_bf16(af[m], bfr[n], acc[m][n], 0, 0, 0);
    }
  }
  #pragma unroll
  for (int m = 0; m < 2; ++m) {
    int row0 = mb + wr * 32 + m * 16 + g * 4;
    #pragma unroll
    for (int n = 0; n < 2; ++n) {
      int col = nb + wc * 32 + n * 16 + li;
      float bval = HAS_BIAS ? bias[col] : 0.0f;
      #pragma unroll
      for (int r = 0; r < 4; ++r) {
        size_t idx = (size_t)(row0 + r) * ldc + col;
        if (BF16_OUT) ((unsigned short*)Cv)[idx] = f2b_rne(acc[m][n][r] + bval);
        else          ((float*)Cv)[idx] = acc[m][n][r] + bval;
      }
    }
  }
}

extern "C" void kernel_launch(void* const* d_in, const int* in_sizes, int n_in,
                              void* d_out, int out_size, void* d_ws, size_t ws_size,
                              hipStream_t stream) {
  const float* x      = (const float*)d_in[0];
  const float* qsW    = (const float*)d_in[1];
  const float* qsb    = (const float*)d_in[2];
  const float* lng    = (const float*)d_in[3];
  const float* lnb    = (const float*)d_in[4];
  const float* qfreq  = (const float*)d_in[5];
  const float* qshift = (const float*)d_in[6];
  const float* Wq     = (const float*)d_in[7];
  const float* Wk     = (const float*)d_in[8];
  const float* Wv     = (const float*)d_in[9];
  const float* Wo     = (const float*)d_in[10];
  const float* bo     = (const float*)d_in[11];
  float* out = (float*)d_out;

  char* ws = (char*)d_ws;
  size_t off = 0;
  auto alloc = [&](size_t bytes) { char* p = ws + off; off += (bytes + 255) & ~(size_t)255; return p; };
  unsigned short* x_bf      = (unsigned short*)alloc((size_t)SEQ * DIMX * 2);
  unsigned short* wqkv_bf   = (unsigned short*)alloc((size_t)QKVN * DIMX * 2);
  unsigned short* wo_bf     = (unsigned short*)alloc((size_t)DIMX * DIMX * 2);
  unsigned short* concat_bf = (unsigned short*)alloc((size_t)SEQ * DIMX * 2);
  unsigned short* qkv_bf    = (unsigned short*)alloc((size_t)SEQ * QKVN * 2);
  unsigned short* qcs       = (unsigned short*)alloc((size_t)QH * SEQ * 128 * 2);
  unsigned short* kcs       = (unsigned short*)alloc((size_t)QH * SEQ * 128 * 2);
  unsigned short* vt        = (unsigned short*)alloc((size_t)TH * HD * SEQ * 2);
  unsigned short* xt        = (unsigned short*)alloc((size_t)QH * HD * SEQ * 2);
  float*          pout      = (float*)alloc((size_t)72 * SEQ * 64 * 4);   // 16+56 slots
  float*          pml       = (float*)alloc((size_t)72 * SEQ * 2 * 4);

  k_f2b_all<<<4736, 256, 0, stream>>>(x, Wq, Wk, Wv, Wo, x_bf, wqkv_bf, wo_bf);
  k_qprep<<<QH * SEQ, 128, 0, stream>>>(x, qsW, qsb, lng, lnb, qfreq, qshift, qcs, kcs);

  // QKV projection -> bf16 qkv  (grid 42x16 = 672 blocks)
  k_gemm64s<0, 1><<<dim3(QKVN / 64, SEQ / 64), 256, 0, stream>>>(
      x_bf, wqkv_bf, qkv_bf, nullptr, DIMX, DIMX, DIMX, QKVN);

  k_tr64all<<<dim3(16, 16), 256, 0, stream>>>(qkv_bf, x_bf, vt, xt);

  // fused attention: quantum lh 0..1 (DQK=128, NT=2, 8 splits), trad (DQK=64, NT=4, 4 splits)
  k_fattn<128, 2><<<dim3(16, QH, 8), 256, 0, stream>>>(
      qcs, (long)SEQ * 128, 128, kcs, (long)SEQ * 128, 128, xt, (long)HD * SEQ, 0, pout, pml);
  k_fattn<64, 4><<<dim3(16, TH, 4), 256, 0, stream>>>(
      qkv_bf, 64, QKVN, qkv_bf + 896, 64, QKVN, vt, (long)HD * SEQ, 16, pout, pml);
  k_fmerge<<<16 * SEQ / 4, 256, 0, stream>>>(pout, pml, concat_bf);

  // output projection (grid 16x16 = 256 blocks) + bias
  k_gemm64s<1, 0><<<dim3(DIMX / 64, SEQ / 64), 256, 0, stream>>>(
      concat_bf, wo_bf, out, bo, DIMX, DIMX, DIMX, DIMX);
}

// Round 9
// 80.708 us; speedup vs baseline: 1.3008x; 1.0102x over previous
//
#include <hip/hip_runtime.h>
#include <hip/hip_bf16.h>
#include <math.h>

#define DIMX 1024
#define SEQ  1024
#define HD   64
#define QH   2
#define TH   14
#define QKVN 2688   // 3*896
#define LN_EPS 1e-5f
#define NB_F2B 4736
#define NB_QPREP 1024
#define NB_XT 32

typedef __bf16 bf16x8 __attribute__((ext_vector_type(8)));
typedef float  f32x4  __attribute__((ext_vector_type(4)));
typedef unsigned short u16x8 __attribute__((ext_vector_type(8)));

__device__ inline unsigned short f2b_rne(float f) {
  unsigned int u = __float_as_uint(f);
  unsigned int r = (u + 0x7FFF + ((u >> 16) & 1)) >> 16;
  return (unsigned short)r;
}

__device__ inline float waveRedSum(float v) {
  #pragma unroll
  for (int off = 32; off; off >>= 1) v += __shfl_xor(v, off, 64);
  return v;
}

// ---------------- prep: f2b converts | quantum prep | x^T for quantum V ----------------
__global__ __launch_bounds__(256) void k_prep(
    const float* __restrict__ x, const float* __restrict__ qsW,
    const float* __restrict__ qsb, const float* __restrict__ lng,
    const float* __restrict__ lnb, const float* __restrict__ qfreq,
    const float* __restrict__ qshift,
    const float* __restrict__ wq, const float* __restrict__ wk,
    const float* __restrict__ wv, const float* __restrict__ wo,
    unsigned short* __restrict__ x_bf, unsigned short* __restrict__ wqkv_bf,
    unsigned short* __restrict__ wo_bf,
    unsigned short* __restrict__ qcs, unsigned short* __restrict__ kcs,
    unsigned short* __restrict__ xt) {
  __shared__ float xrow2[2][HD];
  __shared__ float redm[2][2], redv[2][2];
  __shared__ float qsv2[2][128];
  __shared__ unsigned short ttile[64][72];
  int t = threadIdx.x;
  int bid = blockIdx.x;
  if (bid < NB_F2B) {
    // ---- bf16 conversion: x | wq|wk|wv | wo ----
    long i = ((long)bid * 256 + t) * 4;
    float4 v;
    unsigned short* dst;
    if (i < 1048576) {
      v = *reinterpret_cast<const float4*>(x + i);
      dst = x_bf + i;
    } else if (i < 3801088) {
      long j = i - 1048576;
      const float* s = (j < 917504) ? wq + j
                     : (j < 1835008) ? wk + (j - 917504)
                                     : wv + (j - 1835008);
      v = *reinterpret_cast<const float4*>(s);
      dst = wqkv_bf + j;
    } else {
      long j = i - 3801088;
      v = *reinterpret_cast<const float4*>(wo + j);
      dst = wo_bf + j;
    }
    ushort4 o;
    o.x = f2b_rne(v.x); o.y = f2b_rne(v.y); o.z = f2b_rne(v.z); o.w = f2b_rne(v.w);
    *reinterpret_cast<ushort4*>(dst) = o;
  } else if (bid < NB_F2B + NB_QPREP) {
    // ---- quantum prep, 2 rows per block ----
    int half = t >> 7, o = t & 127;
    int row = (bid - NB_F2B) * 2 + half;
    int h = row >> 10, i = row & 1023;
    if (o < HD) xrow2[half][o] = x[i * DIMX + h * HD + o];
    __syncthreads();
    float s = qsb[o];
    #pragma unroll
    for (int d = 0; d < HD; d += 4) {
      float4 w = *reinterpret_cast<const float4*>(qsW + o * HD + d);
      float4 xv = *reinterpret_cast<const float4*>(&xrow2[half][d]);
      s += xv.x * w.x + xv.y * w.y + xv.z * w.z + xv.w * w.w;
    }
    int wid = (o >> 6), lane = o & 63;
    float ws = waveRedSum(s);
    if (lane == 0) redm[half][wid] = ws;
    __syncthreads();
    float mu = (redm[half][0] + redm[half][1]) * (1.0f / 128.0f);
    float dv = s - mu;
    float ws2 = waveRedSum(dv * dv);
    if (lane == 0) redv[half][wid] = ws2;
    __syncthreads();
    float var = (redv[half][0] + redv[half][1]) * (1.0f / 128.0f);
    float y = dv * rsqrtf(var + LN_EPS) * lng[o] + lnb[o];
    qsv2[half][o] = tanhf(y);
    __syncthreads();
    float freq = qfreq[h], shift = qshift[h];
    size_t base = ((size_t)h * 1024 + i) * 128;
    if (o < HD) {
      float amp = qsv2[half][o];
      float a = qsv2[half][64 + o] * freq + shift;
      float sn, cs;
      __sincosf(a, &sn, &cs);
      qcs[base + o]      = f2b_rne(amp * cs);
      qcs[base + 64 + o] = f2b_rne(amp * sn);
    } else {
      int d = o - 64;
      float amp = qsv2[half][d];
      float bAng = qsv2[half][64 + d] * freq;
      float sn, cs;
      __sincosf(bAng, &sn, &cs);
      kcs[base + d]      = f2b_rne(amp * cs);
      kcs[base + 64 + d] = f2b_rne(amp * sn);
    }
  } else {
    // ---- x^T (quantum V): x[kv][h*64+d] f32 -> xt[h][d][kv] bf16 ----
    int b = bid - (NB_F2B + NB_QPREP);
    int h = b >> 4, kv0 = (b & 15) * 64;
    #pragma unroll
    for (int pass = 0; pass < 2; ++pass) {
      int s = pass * 256 + t;
      int r = s >> 3, c8 = (s & 7) * 8;
      const float* src = x + (size_t)(kv0 + r) * DIMX + h * 64 + c8;
      float4 a = *reinterpret_cast<const float4*>(src);
      float4 b4 = *reinterpret_cast<const float4*>(src + 4);
      ushort4 o1, o2;
      o1.x = f2b_rne(a.x);  o1.y = f2b_rne(a.y);  o1.z = f2b_rne(a.z);  o1.w = f2b_rne(a.w);
      o2.x = f2b_rne(b4.x); o2.y = f2b_rne(b4.y); o2.z = f2b_rne(b4.z); o2.w = f2b_rne(b4.w);
      *reinterpret_cast<ushort4*>(&ttile[r][c8]) = o1;
      *reinterpret_cast<ushort4*>(&ttile[r][c8 + 4]) = o2;
    }
    __syncthreads();
    #pragma unroll
    for (int pass = 0; pass < 2; ++pass) {
      int s = pass * 256 + t;
      int d = s >> 3, k8 = (s & 7) * 8;
      u16x8 o;
      #pragma unroll
      for (int j = 0; j < 8; ++j) o[j] = ttile[k8 + j][d];
      *reinterpret_cast<u16x8*>(xt + (size_t)h * 65536 + (size_t)d * 1024 + kv0 + k8) = o;
    }
  }
}

// ---------------- fused flash attention (device body) ----------------
template <int DQK, int NT>
__device__ __forceinline__ void dev_fattn(
    char* smem,
    const unsigned short* __restrict__ Qp, int ldq,
    const unsigned short* __restrict__ Kp, int ldk,
    const unsigned short* __restrict__ Vp,
    int q0, int split, int slot,
    float* __restrict__ pout, float* __restrict__ pml) {
  const int LQ = DQK + 8;
  const int KREG = DQK / 32;
  unsigned short* Qs  = (unsigned short*)smem;      // 64*LQ
  unsigned short* Ks0 = Qs + 64 * LQ;
  unsigned short* Ks1 = Ks0 + 64 * LQ;
  unsigned short* Vs0 = Ks1 + 64 * LQ;
  unsigned short* Vs1 = Vs0 + 64 * 72;
  unsigned short* Ps  = Vs1 + 64 * 72;
  int kv0 = split * (NT * 64);
  int t = threadIdx.x, lane = t & 63, w = t >> 6;
  int g = lane >> 4, li = lane & 15;

  #pragma unroll
  for (int i = 0; i < DQK / 32; ++i) {
    int s = i * 64 + lane;
    int r = s / (DQK / 8), c8 = (s % (DQK / 8)) * 8;
    u16x8 v = *reinterpret_cast<const u16x8*>(Qp + (size_t)(q0 + w * 16 + r) * ldq + c8);
    *reinterpret_cast<u16x8*>(&Qs[(w * 16 + r) * LQ + c8]) = v;
  }

  u16x8 kreg[KREG], vreg[2];
  auto loadKV = [&](int tile) {
    int j0 = kv0 + tile * 64;
    #pragma unroll
    for (int i = 0; i < KREG; ++i) {
      int s = i * 256 + t;
      int r = s / (DQK / 8), c8 = (s % (DQK / 8)) * 8;
      kreg[i] = *reinterpret_cast<const u16x8*>(Kp + (size_t)(j0 + r) * ldk + c8);
    }
    #pragma unroll
    for (int i = 0; i < 2; ++i) {
      int s = i * 256 + t;
      int d = s >> 3, c8 = (s & 7) * 8;
      vreg[i] = *reinterpret_cast<const u16x8*>(Vp + (size_t)d * 1024 + j0 + c8);
    }
  };
  auto writeKV = [&](int buf) {
    unsigned short* Ksb = buf ? Ks1 : Ks0;
    unsigned short* Vsb = buf ? Vs1 : Vs0;
    #pragma unroll
    for (int i = 0; i < KREG; ++i) {
      int s = i * 256 + t;
      int r = s / (DQK / 8), c8 = (s % (DQK / 8)) * 8;
      *reinterpret_cast<u16x8*>(&Ksb[r * LQ + c8]) = kreg[i];
    }
    #pragma unroll
    for (int i = 0; i < 2; ++i) {
      int s = i * 256 + t;
      int d = s >> 3, c8 = (s & 7) * 8;
      *reinterpret_cast<u16x8*>(&Vsb[d * 72 + c8]) = vreg[i];
    }
  };

  loadKV(0);
  writeKV(0);
  if (NT > 1) loadKV(1);
  __syncthreads();

  f32x4 acc_o[4] = {};
  float mrow[4] = {-1e30f, -1e30f, -1e30f, -1e30f};
  float lrow[4] = {0.f, 0.f, 0.f, 0.f};

  #pragma unroll
  for (int tile = 0; tile < NT; ++tile) {
    int cur = tile & 1;
    unsigned short* Ksc = cur ? Ks1 : Ks0;
    unsigned short* Vsc = cur ? Vs1 : Vs0;
    if (tile < NT - 1) writeKV(cur ^ 1);
    if (tile < NT - 2) loadKV(tile + 2);
    f32x4 s_acc[4] = {};
    #pragma unroll
    for (int kk = 0; kk < DQK / 32; ++kk) {
      bf16x8 aq = *reinterpret_cast<const bf16x8*>(&Qs[(w * 16 + li) * LQ + kk * 32 + g * 8]);
      #pragma unroll
      for (int n = 0; n < 4; ++n) {
        bf16x8 bk = *reinterpret_cast<const bf16x8*>(&Ksc[(n * 16 + li) * LQ + kk * 32 + g * 8]);
        s_acc[n] = __builtin_amdgcn_mfma_f32_16x16x32_bf16(aq, bk, s_acc[n], 0, 0, 0);
      }
    }
    #pragma unroll
    for (int r = 0; r < 4; ++r) {
      float tm = fmaxf(fmaxf(s_acc[0][r], s_acc[1][r]), fmaxf(s_acc[2][r], s_acc[3][r]));
      #pragma unroll
      for (int m = 1; m < 16; m <<= 1) tm = fmaxf(tm, __shfl_xor(tm, m, 64));
      float mn = fmaxf(mrow[r], tm);
      float sf = __expf((mrow[r] - mn) * 0.125f);
      mrow[r] = mn;
      lrow[r] *= sf;
      #pragma unroll
      for (int n = 0; n < 4; ++n) acc_o[n][r] *= sf;
      float rs = 0.f;
      #pragma unroll
      for (int n = 0; n < 4; ++n) {
        float p = __expf((s_acc[n][r] - mn) * 0.125f);
        s_acc[n][r] = p;
        rs += p;
      }
      #pragma unroll
      for (int m = 1; m < 16; m <<= 1) rs += __shfl_xor(rs, m, 64);
      lrow[r] += rs;
    }
    #pragma unroll
    for (int n = 0; n < 4; ++n)
      #pragma unroll
      for (int r = 0; r < 4; ++r)
        Ps[(w * 16 + g * 4 + r) * 72 + n * 16 + li] = f2b_rne(s_acc[n][r]);
    #pragma unroll
    for (int kk = 0; kk < 2; ++kk) {
      bf16x8 ap = *reinterpret_cast<const bf16x8*>(&Ps[(w * 16 + li) * 72 + kk * 32 + g * 8]);
      #pragma unroll
      for (int n = 0; n < 4; ++n) {
        bf16x8 bv = *reinterpret_cast<const bf16x8*>(&Vsc[(n * 16 + li) * 72 + kk * 32 + g * 8]);
        acc_o[n] = __builtin_amdgcn_mfma_f32_16x16x32_bf16(ap, bv, acc_o[n], 0, 0, 0);
      }
    }
    __syncthreads();
  }

  size_t rowbase = (size_t)slot * 1024;
  #pragma unroll
  for (int r = 0; r < 4; ++r) {
    int qr = q0 + w * 16 + g * 4 + r;
    #pragma unroll
    for (int n = 0; n < 4; ++n)
      pout[(rowbase + qr) * 64 + n * 16 + li] = acc_o[n][r];
    if (li == 0) {
      pml[(rowbase + qr) * 2 + 0] = mrow[r];
      pml[(rowbase + qr) * 2 + 1] = lrow[r];
    }
  }
}

// one kernel for both attention classes; blocks 0..255 quantum, 256..1151 trad
__global__ __launch_bounds__(256) void k_fattn_all(
    const unsigned short* __restrict__ qcs, const unsigned short* __restrict__ kcs,
    const unsigned short* __restrict__ xt, const unsigned short* __restrict__ qkv,
    const unsigned short* __restrict__ vt,
    float* __restrict__ pout, float* __restrict__ pml) {
  __shared__ __align__(16) char smem[79872];
  int bid = blockIdx.x;
  if (bid < 256) {
    int qt = bid & 15, h = (bid >> 4) & 1, split = bid >> 5;   // 8 splits, NT=2
    dev_fattn<128, 2>(smem, qcs + (size_t)h * SEQ * 128, 128,
                      kcs + (size_t)h * SEQ * 128, 128,
                      xt + (size_t)h * 65536, qt * 64, split, h * 8 + split, pout, pml);
  } else {
    int b2 = bid - 256;
    int qt = b2 & 15, hs = b2 >> 4;                            // hs 0..55
    int h = hs % 14, split = hs / 14;                          // 4 splits, NT=4
    dev_fattn<64, 4>(smem, qkv + h * 64, QKVN,
                     qkv + 896 + h * 64, QKVN,
                     vt + (size_t)h * 65536, qt * 64, split, 16 + h * 4 + split, pout, pml);
  }
}

// ---------------- merge kv-split partials -> concat bf16 ----------------
__global__ __launch_bounds__(256) void k_fmerge(
    const float* __restrict__ pout, const float* __restrict__ pml,
    unsigned short* __restrict__ concat) {
  int rq = blockIdx.x * 4 + (threadIdx.x >> 6);
  int lh = rq >> 10, q = rq & 1023;
  int d = threadIdx.x & 63;
  int s0 = (lh < 2) ? lh * 8 : 16 + (lh - 2) * 4;
  int ns = (lh < 2) ? 8 : 4;
  float m_s[8], l_s[8];
  float M = -1e30f;
  #pragma unroll
  for (int s = 0; s < 8; ++s) {
    if (s < ns) {
      size_t rb = (size_t)(s0 + s) * 1024 + q;
      m_s[s] = pml[rb * 2 + 0];
      l_s[s] = pml[rb * 2 + 1];
      M = fmaxf(M, m_s[s]);
    }
  }
  float num = 0.f, den = 0.f;
  #pragma unroll
  for (int s = 0; s < 8; ++s) {
    if (s < ns) {
      float wgt = __expf((m_s[s] - M) * 0.125f);
      num += wgt * pout[((size_t)(s0 + s) * 1024 + q) * 64 + d];
      den += wgt * l_s[s];
    }
  }
  concat[(size_t)q * DIMX + lh * 64 + d] = f2b_rne(num / den);
}

// ---------------- 64x64 bf16 MFMA GEMM: global_load_lds + XOR-swizzle ----------------
// If vtp != null and this block's nb covers cols >= 1792 (V region), the epilogue
// writes vt[(col-1792)*1024 + row] (transposed bf16) instead of C.
template <int HAS_BIAS, int BF16_OUT>
__global__ __launch_bounds__(256) void k_gemm64s(
    const unsigned short* __restrict__ A, const unsigned short* __restrict__ B,
    void* __restrict__ Cv, const float* __restrict__ bias,
    unsigned short* __restrict__ vtp,
    int K, int lda, int ldb, int ldc) {
  __shared__ unsigned short As[64 * 64];
  __shared__ unsigned short Bs[64 * 64];
  int t = threadIdx.x, lane = t & 63, w = t >> 6;
  int wr = w >> 1, wc = w & 1;
  int g = lane >> 4, li = lane & 15;
  int mb = blockIdx.y * 64, nb = blockIdx.x * 64;
  int rstg = t >> 3;                          // 0..31
  int cswz = (((t & 7) ^ (rstg & 7)) * 8);    // pre-swizzled global colblock
  f32x4 acc[2][2] = {};
  for (int kb = 0; kb < K; kb += 64) {
    __syncthreads();
    #pragma unroll
    for (int i = 0; i < 2; ++i) {
      __builtin_amdgcn_global_load_lds(
          (const __attribute__((address_space(1))) unsigned int*)(A + (size_t)(mb + i * 32 + rstg) * lda + kb + cswz),
          (__attribute__((address_space(3))) unsigned int*)(As + i * 2048 + t * 8), 16, 0, 0);
      __builtin_amdgcn_global_load_lds(
          (const __attribute__((address_space(1))) unsigned int*)(B + (size_t)(nb + i * 32 + rstg) * ldb + kb + cswz),
          (__attribute__((address_space(3))) unsigned int*)(Bs + i * 2048 + t * 8), 16, 0, 0);
    }
    __syncthreads();
    #pragma unroll
    for (int kk = 0; kk < 2; ++kk) {
      bf16x8 af[2], bfr[2];
      #pragma unroll
      for (int m = 0; m < 2; ++m) {
        int r = wr * 32 + m * 16 + li;
        int cb = kk * 4 + g;
        af[m] = *reinterpret_cast<const bf16x8*>(&As[r * 64 + ((cb ^ (r & 7)) * 8)]);
      }
      #pragma unroll
      for (int n = 0; n < 2; ++n) {
        int r = wc * 32 + n * 16 + li;
        int cb = kk * 4 + g;
        bfr[n] = *reinterpret_cast<const bf16x8*>(&Bs[r * 64 + ((cb ^ (r & 7)) * 8)]);
      }
      #pragma unroll
      for (int m = 0; m < 2; ++m)
        #pragma unroll
        for (int n = 0; n < 2; ++n)
          acc[m][n] = __builtin_amdgcn_mfma_f32_16x16x32_bf16(af[m], bfr[n], acc[m][n], 0, 0, 0);
    }
  }
  if (vtp != nullptr && nb >= 1792) {
    // V region: write transposed bf16 into vt[(col-1792)*1024 + row]
    #pragma unroll
    for (int m = 0; m < 2; ++m) {
      int row0 = mb + wr * 32 + m * 16 + g * 4;
      #pragma unroll
      for (int n = 0; n < 2; ++n) {
        int colrel = nb - 1792 + wc * 32 + n * 16 + li;
        #pragma unroll
        for (int r = 0; r < 4; ++r)
          vtp[(size_t)colrel * 1024 + row0 + r] = f2b_rne(acc[m][n][r]);
      }
    }
    return;
  }
  #pragma unroll
  for (int m = 0; m < 2; ++m) {
    int row0 = mb + wr * 32 + m * 16 + g * 4;
    #pragma unroll
    for (int n = 0; n < 2; ++n) {
      int col = nb + wc * 32 + n * 16 + li;
      float bval = HAS_BIAS ? bias[col] : 0.0f;
      #pragma unroll
      for (int r = 0; r < 4; ++r) {
        size_t idx = (size_t)(row0 + r) * ldc + col;
        if (BF16_OUT) ((unsigned short*)Cv)[idx] = f2b_rne(acc[m][n][r] + bval);
        else          ((float*)Cv)[idx] = acc[m][n][r] + bval;
      }
    }
  }
}

extern "C" void kernel_launch(void* const* d_in, const int* in_sizes, int n_in,
                              void* d_out, int out_size, void* d_ws, size_t ws_size,
                              hipStream_t stream) {
  const float* x      = (const float*)d_in[0];
  const float* qsW    = (const float*)d_in[1];
  const float* qsb    = (const float*)d_in[2];
  const float* lng    = (const float*)d_in[3];
  const float* lnb    = (const float*)d_in[4];
  const float* qfreq  = (const float*)d_in[5];
  const float* qshift = (const float*)d_in[6];
  const float* Wq     = (const float*)d_in[7];
  const float* Wk     = (const float*)d_in[8];
  const float* Wv     = (const float*)d_in[9];
  const float* Wo     = (const float*)d_in[10];
  const float* bo     = (const float*)d_in[11];
  float* out = (float*)d_out;

  char* ws = (char*)d_ws;
  size_t off = 0;
  auto alloc = [&](size_t bytes) { char* p = ws + off; off += (bytes + 255) & ~(size_t)255; return p; };
  unsigned short* x_bf      = (unsigned short*)alloc((size_t)SEQ * DIMX * 2);
  unsigned short* wqkv_bf   = (unsigned short*)alloc((size_t)QKVN * DIMX * 2);
  unsigned short* wo_bf     = (unsigned short*)alloc((size_t)DIMX * DIMX * 2);
  unsigned short* concat_bf = (unsigned short*)alloc((size_t)SEQ * DIMX * 2);
  unsigned short* qkv_bf    = (unsigned short*)alloc((size_t)SEQ * QKVN * 2);
  unsigned short* qcs       = (unsigned short*)alloc((size_t)QH * SEQ * 128 * 2);
  unsigned short* kcs       = (unsigned short*)alloc((size_t)QH * SEQ * 128 * 2);
  unsigned short* vt        = (unsigned short*)alloc((size_t)TH * HD * SEQ * 2);
  unsigned short* xt        = (unsigned short*)alloc((size_t)QH * HD * SEQ * 2);
  float*          pout      = (float*)alloc((size_t)72 * SEQ * 64 * 4);   // 16+56 slots
  float*          pml       = (float*)alloc((size_t)72 * SEQ * 2 * 4);

  // 1. prep: converts + quantum prep + x^T
  k_prep<<<NB_F2B + NB_QPREP + NB_XT, 256, 0, stream>>>(
      x, qsW, qsb, lng, lnb, qfreq, qshift, Wq, Wk, Wv, Wo,
      x_bf, wqkv_bf, wo_bf, qcs, kcs, xt);

  // 2. QKV projection (V tiles go straight to vt transposed)
  k_gemm64s<0, 1><<<dim3(QKVN / 64, SEQ / 64), 256, 0, stream>>>(
      x_bf, wqkv_bf, qkv_bf, nullptr, vt, DIMX, DIMX, DIMX, QKVN);

  // 3. all attention heads, kv-split
  k_fattn_all<<<1152, 256, 0, stream>>>(qcs, kcs, xt, qkv_bf, vt, pout, pml);

  // 4. merge partials
  k_fmerge<<<16 * SEQ / 4, 256, 0, stream>>>(pout, pml, concat_bf);

  // 5. output projection + bias
  k_gemm64s<1, 0><<<dim3(DIMX / 64, SEQ / 64), 256, 0, stream>>>(
      concat_bf, wo_bf, out, bo, nullptr, DIMX, DIMX, DIMX, DIMX);
}

// Round 10
// 79.625 us; speedup vs baseline: 1.3185x; 1.0136x over previous
//
#include <hip/hip_runtime.h>
#include <hip/hip_bf16.h>
#include <math.h>

#define DIMX 1024
#define SEQ  1024
#define HD   64
#define QH   2
#define TH   14
#define QKVN 2688   // 3*896
#define LN_EPS 1e-5f
#define NB_F2B 4736
#define NB_QPREP 1024
#define NB_XT 32

typedef __bf16 bf16x8 __attribute__((ext_vector_type(8)));
typedef float  f32x4  __attribute__((ext_vector_type(4)));
typedef unsigned short u16x8 __attribute__((ext_vector_type(8)));

__device__ inline unsigned short f2b_rne(float f) {
  unsigned int u = __float_as_uint(f);
  unsigned int r = (u + 0x7FFF + ((u >> 16) & 1)) >> 16;
  return (unsigned short)r;
}

__device__ inline float waveRedSum(float v) {
  #pragma unroll
  for (int off = 32; off; off >>= 1) v += __shfl_xor(v, off, 64);
  return v;
}

// ---------------- prep: f2b converts | quantum prep | x^T for quantum V ----------------
__global__ __launch_bounds__(256) void k_prep(
    const float* __restrict__ x, const float* __restrict__ qsW,
    const float* __restrict__ qsb, const float* __restrict__ lng,
    const float* __restrict__ lnb, const float* __restrict__ qfreq,
    const float* __restrict__ qshift,
    const float* __restrict__ wq, const float* __restrict__ wk,
    const float* __restrict__ wv, const float* __restrict__ wo,
    unsigned short* __restrict__ x_bf, unsigned short* __restrict__ wqkv_bf,
    unsigned short* __restrict__ wo_bf,
    unsigned short* __restrict__ qcs, unsigned short* __restrict__ kcs,
    unsigned short* __restrict__ xt) {
  __shared__ float xrow2[2][HD];
  __shared__ float redm[2][2], redv[2][2];
  __shared__ float qsv2[2][128];
  __shared__ unsigned short ttile[64][72];
  int t = threadIdx.x;
  int bid = blockIdx.x;
  if (bid < NB_F2B) {
    long i = ((long)bid * 256 + t) * 4;
    float4 v;
    unsigned short* dst;
    if (i < 1048576) {
      v = *reinterpret_cast<const float4*>(x + i);
      dst = x_bf + i;
    } else if (i < 3801088) {
      long j = i - 1048576;
      const float* s = (j < 917504) ? wq + j
                     : (j < 1835008) ? wk + (j - 917504)
                                     : wv + (j - 1835008);
      v = *reinterpret_cast<const float4*>(s);
      dst = wqkv_bf + j;
    } else {
      long j = i - 3801088;
      v = *reinterpret_cast<const float4*>(wo + j);
      dst = wo_bf + j;
    }
    ushort4 o;
    o.x = f2b_rne(v.x); o.y = f2b_rne(v.y); o.z = f2b_rne(v.z); o.w = f2b_rne(v.w);
    *reinterpret_cast<ushort4*>(dst) = o;
  } else if (bid < NB_F2B + NB_QPREP) {
    int half = t >> 7, o = t & 127;
    int row = (bid - NB_F2B) * 2 + half;
    int h = row >> 10, i = row & 1023;
    if (o < HD) xrow2[half][o] = x[i * DIMX + h * HD + o];
    __syncthreads();
    float s = qsb[o];
    #pragma unroll
    for (int d = 0; d < HD; d += 4) {
      float4 w = *reinterpret_cast<const float4*>(qsW + o * HD + d);
      float4 xv = *reinterpret_cast<const float4*>(&xrow2[half][d]);
      s += xv.x * w.x + xv.y * w.y + xv.z * w.z + xv.w * w.w;
    }
    int wid = (o >> 6), lane = o & 63;
    float ws = waveRedSum(s);
    if (lane == 0) redm[half][wid] = ws;
    __syncthreads();
    float mu = (redm[half][0] + redm[half][1]) * (1.0f / 128.0f);
    float dv = s - mu;
    float ws2 = waveRedSum(dv * dv);
    if (lane == 0) redv[half][wid] = ws2;
    __syncthreads();
    float var = (redv[half][0] + redv[half][1]) * (1.0f / 128.0f);
    float y = dv * rsqrtf(var + LN_EPS) * lng[o] + lnb[o];
    qsv2[half][o] = tanhf(y);
    __syncthreads();
    float freq = qfreq[h], shift = qshift[h];
    size_t base = ((size_t)h * 1024 + i) * 128;
    if (o < HD) {
      float amp = qsv2[half][o];
      float a = qsv2[half][64 + o] * freq + shift;
      float sn, cs;
      __sincosf(a, &sn, &cs);
      qcs[base + o]      = f2b_rne(amp * cs);
      qcs[base + 64 + o] = f2b_rne(amp * sn);
    } else {
      int d = o - 64;
      float amp = qsv2[half][d];
      float bAng = qsv2[half][64 + d] * freq;
      float sn, cs;
      __sincosf(bAng, &sn, &cs);
      kcs[base + d]      = f2b_rne(amp * cs);
      kcs[base + 64 + d] = f2b_rne(amp * sn);
    }
  } else {
    int b = bid - (NB_F2B + NB_QPREP);
    int h = b >> 4, kv0 = (b & 15) * 64;
    #pragma unroll
    for (int pass = 0; pass < 2; ++pass) {
      int s = pass * 256 + t;
      int r = s >> 3, c8 = (s & 7) * 8;
      const float* src = x + (size_t)(kv0 + r) * DIMX + h * 64 + c8;
      float4 a = *reinterpret_cast<const float4*>(src);
      float4 b4 = *reinterpret_cast<const float4*>(src + 4);
      ushort4 o1, o2;
      o1.x = f2b_rne(a.x);  o1.y = f2b_rne(a.y);  o1.z = f2b_rne(a.z);  o1.w = f2b_rne(a.w);
      o2.x = f2b_rne(b4.x); o2.y = f2b_rne(b4.y); o2.z = f2b_rne(b4.z); o2.w = f2b_rne(b4.w);
      *reinterpret_cast<ushort4*>(&ttile[r][c8]) = o1;
      *reinterpret_cast<ushort4*>(&ttile[r][c8 + 4]) = o2;
    }
    __syncthreads();
    #pragma unroll
    for (int pass = 0; pass < 2; ++pass) {
      int s = pass * 256 + t;
      int d = s >> 3, k8 = (s & 7) * 8;
      u16x8 o;
      #pragma unroll
      for (int j = 0; j < 8; ++j) o[j] = ttile[k8 + j][d];
      *reinterpret_cast<u16x8*>(xt + (size_t)h * 65536 + (size_t)d * 1024 + kv0 + k8) = o;
    }
  }
}

// ---------------- flash attention, batch-softmax: scores in regs, one softmax pass ----
// Phase 1: QK^T over NT tiles (K via LDS dbuf). Phase 2: single softmax (block-local
// max; merge handles cross-split). Phase 3: PV (V time-shares K's LDS buffers).
template <int DQK, int NT>
__global__ __launch_bounds__(256) void k_fattn2(
    const unsigned short* __restrict__ Qb, long q_hstep, int ldq,
    const unsigned short* __restrict__ Kb, long k_hstep, int ldk,
    const unsigned short* __restrict__ Vtb, long v_hstep, int slot0,
    float* __restrict__ pout, float* __restrict__ pml) {
  const int LQ = DQK + 8;
  const int KREG = DQK / 32;
  __shared__ unsigned short Qs[64 * (DQK + 8)];
  __shared__ unsigned short KV0[64 * (DQK + 8)];   // K tile dbuf; V reuses (stride 72)
  __shared__ unsigned short KV1[64 * (DQK + 8)];
  __shared__ unsigned short Ps[64 * 72];
  int h = blockIdx.y, q0 = blockIdx.x * 64, split = blockIdx.z;
  int kv0 = split * (NT * 64);
  int slot = slot0 + h * gridDim.z + split;
  int t = threadIdx.x, lane = t & 63, w = t >> 6;
  int g = lane >> 4, li = lane & 15;
  const unsigned short* Qp = Qb + (size_t)h * q_hstep;
  const unsigned short* Kp = Kb + (size_t)h * k_hstep;
  const unsigned short* Vp = Vtb + (size_t)h * v_hstep;

  // Q stage (per-wave rows)
  #pragma unroll
  for (int i = 0; i < DQK / 32; ++i) {
    int s = i * 64 + lane;
    int r = s / (DQK / 8), c8 = (s % (DQK / 8)) * 8;
    u16x8 v = *reinterpret_cast<const u16x8*>(Qp + (size_t)(q0 + w * 16 + r) * ldq + c8);
    *reinterpret_cast<u16x8*>(&Qs[(w * 16 + r) * LQ + c8]) = v;
  }

  u16x8 kreg[KREG], vreg[2];
  auto loadK = [&](int tile) {
    int j0 = kv0 + tile * 64;
    #pragma unroll
    for (int i = 0; i < KREG; ++i) {
      int s = i * 256 + t;
      int r = s / (DQK / 8), c8 = (s % (DQK / 8)) * 8;
      kreg[i] = *reinterpret_cast<const u16x8*>(Kp + (size_t)(j0 + r) * ldk + c8);
    }
  };
  auto writeK = [&](int buf) {
    unsigned short* Kd = buf ? KV1 : KV0;
    #pragma unroll
    for (int i = 0; i < KREG; ++i) {
      int s = i * 256 + t;
      int r = s / (DQK / 8), c8 = (s % (DQK / 8)) * 8;
      *reinterpret_cast<u16x8*>(&Kd[r * LQ + c8]) = kreg[i];
    }
  };
  auto loadV = [&](int tile) {
    int j0 = kv0 + tile * 64;
    #pragma unroll
    for (int i = 0; i < 2; ++i) {
      int s = i * 256 + t;
      int d = s >> 3, c8 = (s & 7) * 8;
      vreg[i] = *reinterpret_cast<const u16x8*>(Vp + (size_t)d * 1024 + j0 + c8);
    }
  };
  auto writeV = [&](int buf) {
    unsigned short* Vd = buf ? KV1 : KV0;
    #pragma unroll
    for (int i = 0; i < 2; ++i) {
      int s = i * 256 + t;
      int d = s >> 3, c8 = (s & 7) * 8;
      *reinterpret_cast<u16x8*>(&Vd[d * 72 + c8]) = vreg[i];
    }
  };

  loadK(0); writeK(0); loadK(1); loadV(0);
  __syncthreads();

  f32x4 s_all[NT][4] = {};

  // phase 1: QK^T, all NT tiles
  #pragma unroll
  for (int tile = 0; tile < NT; ++tile) {
    const unsigned short* Ksc = (tile & 1) ? KV1 : KV0;
    if (tile < NT - 1) writeK((tile + 1) & 1);
    if (tile < NT - 2) loadK(tile + 2);
    if (tile == NT - 1) writeV(0);   // V0 -> KV0 (its last K read ended 2 tiles ago)
    #pragma unroll
    for (int kk = 0; kk < DQK / 32; ++kk) {
      bf16x8 aq = *reinterpret_cast<const bf16x8*>(&Qs[(w * 16 + li) * LQ + kk * 32 + g * 8]);
      #pragma unroll
      for (int n = 0; n < 4; ++n) {
        bf16x8 bk = *reinterpret_cast<const bf16x8*>(&Ksc[(n * 16 + li) * LQ + kk * 32 + g * 8]);
        s_all[tile][n] = __builtin_amdgcn_mfma_f32_16x16x32_bf16(aq, bk, s_all[tile][n], 0, 0, 0);
      }
    }
    __syncthreads();
  }

  loadV(1);

  // phase 2: one softmax pass (C-layout: row = g*4+r, cols spread over li,n,tile)
  float mrow[4], lrow[4];
  #pragma unroll
  for (int r = 0; r < 4; ++r) {
    float tm = -1e30f;
    #pragma unroll
    for (int tile = 0; tile < NT; ++tile)
      #pragma unroll
      for (int n = 0; n < 4; ++n) tm = fmaxf(tm, s_all[tile][n][r]);
    #pragma unroll
    for (int m = 1; m < 16; m <<= 1) tm = fmaxf(tm, __shfl_xor(tm, m, 64));
    float rs = 0.f;
    #pragma unroll
    for (int tile = 0; tile < NT; ++tile)
      #pragma unroll
      for (int n = 0; n < 4; ++n) {
        float p = __expf((s_all[tile][n][r] - tm) * 0.125f);
        s_all[tile][n][r] = p;
        rs += p;
      }
    #pragma unroll
    for (int m = 1; m < 16; m <<= 1) rs += __shfl_xor(rs, m, 64);
    mrow[r] = tm; lrow[r] = rs;
  }

  // phase 3: PV over NT tiles (V dbuf in KV0/KV1; Ps wave-local, no barrier needed)
  f32x4 acc_o[4] = {};
  #pragma unroll
  for (int tile = 0; tile < NT; ++tile) {
    const unsigned short* Vsc = (tile & 1) ? KV1 : KV0;
    if (tile < NT - 1) writeV((tile + 1) & 1);
    if (tile < NT - 2) loadV(tile + 2);
    #pragma unroll
    for (int n = 0; n < 4; ++n)
      #pragma unroll
      for (int r = 0; r < 4; ++r)
        Ps[(w * 16 + g * 4 + r) * 72 + n * 16 + li] = f2b_rne(s_all[tile][n][r]);
    #pragma unroll
    for (int kk = 0; kk < 2; ++kk) {
      bf16x8 ap = *reinterpret_cast<const bf16x8*>(&Ps[(w * 16 + li) * 72 + kk * 32 + g * 8]);
      #pragma unroll
      for (int n = 0; n < 4; ++n) {
        bf16x8 bv = *reinterpret_cast<const bf16x8*>(&Vsc[(n * 16 + li) * 72 + kk * 32 + g * 8]);
        acc_o[n] = __builtin_amdgcn_mfma_f32_16x16x32_bf16(ap, bv, acc_o[n], 0, 0, 0);
      }
    }
    __syncthreads();
  }

  size_t rowbase = (size_t)slot * 1024;
  #pragma unroll
  for (int r = 0; r < 4; ++r) {
    int qr = q0 + w * 16 + g * 4 + r;
    #pragma unroll
    for (int n = 0; n < 4; ++n)
      pout[(rowbase + qr) * 64 + n * 16 + li] = acc_o[n][r];
    if (li == 0) {
      pml[(rowbase + qr) * 2 + 0] = mrow[r];
      pml[(rowbase + qr) * 2 + 1] = lrow[r];
    }
  }
}

// ---------------- merge kv-split partials -> concat bf16 ----------------
__global__ __launch_bounds__(256) void k_fmerge(
    const float* __restrict__ pout, const float* __restrict__ pml,
    unsigned short* __restrict__ concat) {
  int rq = blockIdx.x * 4 + (threadIdx.x >> 6);
  int lh = rq >> 10, q = rq & 1023;
  int d = threadIdx.x & 63;
  int s0 = (lh < 2) ? lh * 8 : 16 + (lh - 2) * 4;
  int ns = (lh < 2) ? 8 : 4;
  float m_s[8], l_s[8];
  float M = -1e30f;
  #pragma unroll
  for (int s = 0; s < 8; ++s) {
    if (s < ns) {
      size_t rb = (size_t)(s0 + s) * 1024 + q;
      m_s[s] = pml[rb * 2 + 0];
      l_s[s] = pml[rb * 2 + 1];
      M = fmaxf(M, m_s[s]);
    }
  }
  float num = 0.f, den = 0.f;
  #pragma unroll
  for (int s = 0; s < 8; ++s) {
    if (s < ns) {
      float wgt = __expf((m_s[s] - M) * 0.125f);
      num += wgt * pout[((size_t)(s0 + s) * 1024 + q) * 64 + d];
      den += wgt * l_s[s];
    }
  }
  concat[(size_t)q * DIMX + lh * 64 + d] = f2b_rne(num / den);
}

// ---------------- 64x64 bf16 MFMA GEMM: global_load_lds + XOR-swizzle ----------------
template <int HAS_BIAS, int BF16_OUT>
__global__ __launch_bounds__(256) void k_gemm64s(
    const unsigned short* __restrict__ A, const unsigned short* __restrict__ B,
    void* __restrict__ Cv, const float* __restrict__ bias,
    unsigned short* __restrict__ vtp,
    int K, int lda, int ldb, int ldc) {
  __shared__ unsigned short As[64 * 64];
  __shared__ unsigned short Bs[64 * 64];
  int t = threadIdx.x, lane = t & 63, w = t >> 6;
  int wr = w >> 1, wc = w & 1;
  int g = lane >> 4, li = lane & 15;
  int mb = blockIdx.y * 64, nb = blockIdx.x * 64;
  int rstg = t >> 3;
  int cswz = (((t & 7) ^ (rstg & 7)) * 8);
  f32x4 acc[2][2] = {};
  for (int kb = 0; kb < K; kb += 64) {
    __syncthreads();
    #pragma unroll
    for (int i = 0; i < 2; ++i) {
      __builtin_amdgcn_global_load_lds(
          (const __attribute__((address_space(1))) unsigned int*)(A + (size_t)(mb + i * 32 + rstg) * lda + kb + cswz),
          (__attribute__((address_space(3))) unsigned int*)(As + i * 2048 + t * 8), 16, 0, 0);
      __builtin_amdgcn_global_load_lds(
          (const __attribute__((address_space(1))) unsigned int*)(B + (size_t)(nb + i * 32 + rstg) * ldb + kb + cswz),
          (__attribute__((address_space(3))) unsigned int*)(Bs + i * 2048 + t * 8), 16, 0, 0);
    }
    __syncthreads();
    #pragma unroll
    for (int kk = 0; kk < 2; ++kk) {
      bf16x8 af[2], bfr[2];
      #pragma unroll
      for (int m = 0; m < 2; ++m) {
        int r = wr * 32 + m * 16 + li;
        int cb = kk * 4 + g;
        af[m] = *reinterpret_cast<const bf16x8*>(&As[r * 64 + ((cb ^ (r & 7)) * 8)]);
      }
      #pragma unroll
      for (int n = 0; n < 2; ++n) {
        int r = wc * 32 + n * 16 + li;
        int cb = kk * 4 + g;
        bfr[n] = *reinterpret_cast<const bf16x8*>(&Bs[r * 64 + ((cb ^ (r & 7)) * 8)]);
      }
      #pragma unroll
      for (int m = 0; m < 2; ++m)
        #pragma unroll
        for (int n = 0; n < 2; ++n)
          acc[m][n] = __builtin_amdgcn_mfma_f32_16x16x32_bf16(af[m], bfr[n], acc[m][n], 0, 0, 0);
    }
  }
  if (vtp != nullptr && nb >= 1792) {
    #pragma unroll
    for (int m = 0; m < 2; ++m) {
      int row0 = mb + wr * 32 + m * 16 + g * 4;
      #pragma unroll
      for (int n = 0; n < 2; ++n) {
        int colrel = nb - 1792 + wc * 32 + n * 16 + li;
        #pragma unroll
        for (int r = 0; r < 4; ++r)
          vtp[(size_t)colrel * 1024 + row0 + r] = f2b_rne(acc[m][n][r]);
      }
    }
    return;
  }
  #pragma unroll
  for (int m = 0; m < 2; ++m) {
    int row0 = mb + wr * 32 + m * 16 + g * 4;
    #pragma unroll
    for (int n = 0; n < 2; ++n) {
      int col = nb + wc * 32 + n * 16 + li;
      float bval = HAS_BIAS ? bias[col] : 0.0f;
      #pragma unroll
      for (int r = 0; r < 4; ++r) {
        size_t idx = (size_t)(row0 + r) * ldc + col;
        if (BF16_OUT) ((unsigned short*)Cv)[idx] = f2b_rne(acc[m][n][r] + bval);
        else          ((float*)Cv)[idx] = acc[m][n][r] + bval;
      }
    }
  }
}

extern "C" void kernel_launch(void* const* d_in, const int* in_sizes, int n_in,
                              void* d_out, int out_size, void* d_ws, size_t ws_size,
                              hipStream_t stream) {
  const float* x      = (const float*)d_in[0];
  const float* qsW    = (const float*)d_in[1];
  const float* qsb    = (const float*)d_in[2];
  const float* lng    = (const float*)d_in[3];
  const float* lnb    = (const float*)d_in[4];
  const float* qfreq  = (const float*)d_in[5];
  const float* qshift = (const float*)d_in[6];
  const float* Wq     = (const float*)d_in[7];
  const float* Wk     = (const float*)d_in[8];
  const float* Wv     = (const float*)d_in[9];
  const float* Wo     = (const float*)d_in[10];
  const float* bo     = (const float*)d_in[11];
  float* out = (float*)d_out;

  char* ws = (char*)d_ws;
  size_t off = 0;
  auto alloc = [&](size_t bytes) { char* p = ws + off; off += (bytes + 255) & ~(size_t)255; return p; };
  unsigned short* x_bf      = (unsigned short*)alloc((size_t)SEQ * DIMX * 2);
  unsigned short* wqkv_bf   = (unsigned short*)alloc((size_t)QKVN * DIMX * 2);
  unsigned short* wo_bf     = (unsigned short*)alloc((size_t)DIMX * DIMX * 2);
  unsigned short* concat_bf = (unsigned short*)alloc((size_t)SEQ * DIMX * 2);
  unsigned short* qkv_bf    = (unsigned short*)alloc((size_t)SEQ * QKVN * 2);
  unsigned short* qcs       = (unsigned short*)alloc((size_t)QH * SEQ * 128 * 2);
  unsigned short* kcs       = (unsigned short*)alloc((size_t)QH * SEQ * 128 * 2);
  unsigned short* vt        = (unsigned short*)alloc((size_t)TH * HD * SEQ * 2);
  unsigned short* xt        = (unsigned short*)alloc((size_t)QH * HD * SEQ * 2);
  float*          pout      = (float*)alloc((size_t)72 * SEQ * 64 * 4);
  float*          pml       = (float*)alloc((size_t)72 * SEQ * 2 * 4);

  // 1. prep
  k_prep<<<NB_F2B + NB_QPREP + NB_XT, 256, 0, stream>>>(
      x, qsW, qsb, lng, lnb, qfreq, qshift, Wq, Wk, Wv, Wo,
      x_bf, wqkv_bf, wo_bf, qcs, kcs, xt);

  // 2. QKV projection (V tiles straight to vt transposed)
  k_gemm64s<0, 1><<<dim3(QKVN / 64, SEQ / 64), 256, 0, stream>>>(
      x_bf, wqkv_bf, qkv_bf, nullptr, vt, DIMX, DIMX, DIMX, QKVN);

  // 3. attention: trad (36 KB LDS, 4 blocks/CU), quantum (60 KB)
  k_fattn2<64, 4><<<dim3(16, TH, 4), 256, 0, stream>>>(
      qkv_bf, 64, QKVN, qkv_bf + 896, 64, QKVN, vt, (long)HD * SEQ, 16, pout, pml);
  k_fattn2<128, 2><<<dim3(16, QH, 8), 256, 0, stream>>>(
      qcs, (long)SEQ * 128, 128, kcs, (long)SEQ * 128, 128, xt, (long)HD * SEQ, 0, pout, pml);

  // 4. merge
  k_fmerge<<<16 * SEQ / 4, 256, 0, stream>>>(pout, pml, concat_bf);

  // 5. output projection + bias
  k_gemm64s<1, 0><<<dim3(DIMX / 64, SEQ / 64), 256, 0, stream>>>(
      concat_bf, wo_bf, out, bo, nullptr, DIMX, DIMX, DIMX, DIMX);
}

// Round 11
// 77.661 us; speedup vs baseline: 1.3518x; 1.0253x over previous
//
#include <hip/hip_runtime.h>
#include <hip/hip_bf16.h>
#include <math.h>

#define DIMX 1024
#define SEQ  1024
#define HD   64
#define QH   2
#define TH   14
#define QKVN 2688   // 3*896
#define LN_EPS 1e-5f
#define NB_F2B 4736
#define NB_QPREP 1024
#define NB_XT 32

typedef __bf16 bf16x8 __attribute__((ext_vector_type(8)));
typedef float  f32x4  __attribute__((ext_vector_type(4)));
typedef unsigned short u16x8 __attribute__((ext_vector_type(8)));

__device__ inline unsigned short f2b_rne(float f) {
  unsigned int u = __float_as_uint(f);
  unsigned int r = (u + 0x7FFF + ((u >> 16) & 1)) >> 16;
  return (unsigned short)r;
}

__device__ inline float waveRedSum(float v) {
  #pragma unroll
  for (int off = 32; off; off >>= 1) v += __shfl_xor(v, off, 64);
  return v;
}

// ---------------- prep: f2b converts | quantum prep | x^T for quantum V ----------------
__global__ __launch_bounds__(256) void k_prep(
    const float* __restrict__ x, const float* __restrict__ qsW,
    const float* __restrict__ qsb, const float* __restrict__ lng,
    const float* __restrict__ lnb, const float* __restrict__ qfreq,
    const float* __restrict__ qshift,
    const float* __restrict__ wq, const float* __restrict__ wk,
    const float* __restrict__ wv, const float* __restrict__ wo,
    unsigned short* __restrict__ x_bf, unsigned short* __restrict__ wqkv_bf,
    unsigned short* __restrict__ wo_bf,
    unsigned short* __restrict__ qcs, unsigned short* __restrict__ kcs,
    unsigned short* __restrict__ xt) {
  __shared__ float xrow2[2][HD];
  __shared__ float redm[2][2], redv[2][2];
  __shared__ float qsv2[2][128];
  __shared__ unsigned short ttile[64][72];
  int t = threadIdx.x;
  int bid = blockIdx.x;
  if (bid < NB_F2B) {
    long i = ((long)bid * 256 + t) * 4;
    float4 v;
    unsigned short* dst;
    if (i < 1048576) {
      v = *reinterpret_cast<const float4*>(x + i);
      dst = x_bf + i;
    } else if (i < 3801088) {
      long j = i - 1048576;
      const float* s = (j < 917504) ? wq + j
                     : (j < 1835008) ? wk + (j - 917504)
                                     : wv + (j - 1835008);
      v = *reinterpret_cast<const float4*>(s);
      dst = wqkv_bf + j;
    } else {
      long j = i - 3801088;
      v = *reinterpret_cast<const float4*>(wo + j);
      dst = wo_bf + j;
    }
    ushort4 o;
    o.x = f2b_rne(v.x); o.y = f2b_rne(v.y); o.z = f2b_rne(v.z); o.w = f2b_rne(v.w);
    *reinterpret_cast<ushort4*>(dst) = o;
  } else if (bid < NB_F2B + NB_QPREP) {
    int half = t >> 7, o = t & 127;
    int row = (bid - NB_F2B) * 2 + half;
    int h = row >> 10, i = row & 1023;
    if (o < HD) xrow2[half][o] = x[i * DIMX + h * HD + o];
    __syncthreads();
    float s = qsb[o];
    #pragma unroll
    for (int d = 0; d < HD; d += 4) {
      float4 w = *reinterpret_cast<const float4*>(qsW + o * HD + d);
      float4 xv = *reinterpret_cast<const float4*>(&xrow2[half][d]);
      s += xv.x * w.x + xv.y * w.y + xv.z * w.z + xv.w * w.w;
    }
    int wid = (o >> 6), lane = o & 63;
    float ws = waveRedSum(s);
    if (lane == 0) redm[half][wid] = ws;
    __syncthreads();
    float mu = (redm[half][0] + redm[half][1]) * (1.0f / 128.0f);
    float dv = s - mu;
    float ws2 = waveRedSum(dv * dv);
    if (lane == 0) redv[half][wid] = ws2;
    __syncthreads();
    float var = (redv[half][0] + redv[half][1]) * (1.0f / 128.0f);
    float y = dv * rsqrtf(var + LN_EPS) * lng[o] + lnb[o];
    qsv2[half][o] = tanhf(y);
    __syncthreads();
    float freq = qfreq[h], shift = qshift[h];
    size_t base = ((size_t)h * 1024 + i) * 128;
    if (o < HD) {
      float amp = qsv2[half][o];
      float a = qsv2[half][64 + o] * freq + shift;
      float sn, cs;
      __sincosf(a, &sn, &cs);
      qcs[base + o]      = f2b_rne(amp * cs);
      qcs[base + 64 + o] = f2b_rne(amp * sn);
    } else {
      int d = o - 64;
      float amp = qsv2[half][d];
      float bAng = qsv2[half][64 + d] * freq;
      float sn, cs;
      __sincosf(bAng, &sn, &cs);
      kcs[base + d]      = f2b_rne(amp * cs);
      kcs[base + 64 + d] = f2b_rne(amp * sn);
    }
  } else {
    int b = bid - (NB_F2B + NB_QPREP);
    int h = b >> 4, kv0 = (b & 15) * 64;
    #pragma unroll
    for (int pass = 0; pass < 2; ++pass) {
      int s = pass * 256 + t;
      int r = s >> 3, c8 = (s & 7) * 8;
      const float* src = x + (size_t)(kv0 + r) * DIMX + h * 64 + c8;
      float4 a = *reinterpret_cast<const float4*>(src);
      float4 b4 = *reinterpret_cast<const float4*>(src + 4);
      ushort4 o1, o2;
      o1.x = f2b_rne(a.x);  o1.y = f2b_rne(a.y);  o1.z = f2b_rne(a.z);  o1.w = f2b_rne(a.w);
      o2.x = f2b_rne(b4.x); o2.y = f2b_rne(b4.y); o2.z = f2b_rne(b4.z); o2.w = f2b_rne(b4.w);
      *reinterpret_cast<ushort4*>(&ttile[r][c8]) = o1;
      *reinterpret_cast<ushort4*>(&ttile[r][c8 + 4]) = o2;
    }
    __syncthreads();
    #pragma unroll
    for (int pass = 0; pass < 2; ++pass) {
      int s = pass * 256 + t;
      int d = s >> 3, k8 = (s & 7) * 8;
      u16x8 o;
      #pragma unroll
      for (int j = 0; j < 8; ++j) o[j] = ttile[k8 + j][d];
      *reinterpret_cast<u16x8*>(xt + (size_t)h * 65536 + (size_t)d * 1024 + kv0 + k8) = o;
    }
  }
}

// ---------------- flash attention device body (batch-softmax, Q in registers) --------
template <int DQK, int NT>
__device__ __forceinline__ void dev_fattn2(
    char* smem,
    const unsigned short* __restrict__ Qp, int ldq,
    const unsigned short* __restrict__ Kp, int ldk,
    const unsigned short* __restrict__ Vp,
    int q0, int kv0, int slot,
    float* __restrict__ pout, float* __restrict__ pml) {
  const int LQ = DQK + 8;
  const int KREG = DQK / 32;
  unsigned short* KV0 = (unsigned short*)smem;       // K stride LQ; V reuses stride 72
  unsigned short* KV1 = KV0 + 64 * LQ;
  unsigned short* Ps  = KV1 + 64 * LQ;
  int t = threadIdx.x, lane = t & 63, w = t >> 6;
  int g = lane >> 4, li = lane & 15;

  // Q fragments directly into registers (lane li owns row q0+w*16+li)
  bf16x8 aq[KREG];
  #pragma unroll
  for (int kk = 0; kk < KREG; ++kk)
    aq[kk] = *reinterpret_cast<const bf16x8*>(
        Qp + (size_t)(q0 + w * 16 + li) * ldq + kk * 32 + g * 8);

  u16x8 kreg[KREG], vreg[2];
  auto loadK = [&](int tile) {
    int j0 = kv0 + tile * 64;
    #pragma unroll
    for (int i = 0; i < KREG; ++i) {
      int s = i * 256 + t;
      int r = s / (DQK / 8), c8 = (s % (DQK / 8)) * 8;
      kreg[i] = *reinterpret_cast<const u16x8*>(Kp + (size_t)(j0 + r) * ldk + c8);
    }
  };
  auto writeK = [&](int buf) {
    unsigned short* Kd = buf ? KV1 : KV0;
    #pragma unroll
    for (int i = 0; i < KREG; ++i) {
      int s = i * 256 + t;
      int r = s / (DQK / 8), c8 = (s % (DQK / 8)) * 8;
      *reinterpret_cast<u16x8*>(&Kd[r * LQ + c8]) = kreg[i];
    }
  };
  auto loadV = [&](int tile) {
    int j0 = kv0 + tile * 64;
    #pragma unroll
    for (int i = 0; i < 2; ++i) {
      int s = i * 256 + t;
      int d = s >> 3, c8 = (s & 7) * 8;
      vreg[i] = *reinterpret_cast<const u16x8*>(Vp + (size_t)d * 1024 + j0 + c8);
    }
  };
  auto writeV = [&](int buf) {
    unsigned short* Vd = buf ? KV1 : KV0;
    #pragma unroll
    for (int i = 0; i < 2; ++i) {
      int s = i * 256 + t;
      int d = s >> 3, c8 = (s & 7) * 8;
      *reinterpret_cast<u16x8*>(&Vd[d * 72 + c8]) = vreg[i];
    }
  };

  loadK(0); writeK(0);
  if (NT > 1) loadK(1);
  loadV(0);
  __syncthreads();

  f32x4 s_all[NT][4] = {};

  // phase 1: QK^T over all NT tiles
  #pragma unroll
  for (int tile = 0; tile < NT; ++tile) {
    const unsigned short* Ksc = (tile & 1) ? KV1 : KV0;
    if (tile < NT - 1) writeK((tile + 1) & 1);
    if (tile < NT - 2) loadK(tile + 2);
    if (tile == NT - 1) writeV(0);
    #pragma unroll
    for (int kk = 0; kk < KREG; ++kk) {
      #pragma unroll
      for (int n = 0; n < 4; ++n) {
        bf16x8 bk = *reinterpret_cast<const bf16x8*>(&Ksc[(n * 16 + li) * LQ + kk * 32 + g * 8]);
        s_all[tile][n] = __builtin_amdgcn_mfma_f32_16x16x32_bf16(aq[kk], bk, s_all[tile][n], 0, 0, 0);
      }
    }
    __syncthreads();
  }

  if (NT > 1) loadV(1);

  // phase 2: single softmax pass (block-local max; merge handles cross-split)
  float mrow[4], lrow[4];
  #pragma unroll
  for (int r = 0; r < 4; ++r) {
    float tm = -1e30f;
    #pragma unroll
    for (int tile = 0; tile < NT; ++tile)
      #pragma unroll
      for (int n = 0; n < 4; ++n) tm = fmaxf(tm, s_all[tile][n][r]);
    #pragma unroll
    for (int m = 1; m < 16; m <<= 1) tm = fmaxf(tm, __shfl_xor(tm, m, 64));
    float rs = 0.f;
    #pragma unroll
    for (int tile = 0; tile < NT; ++tile)
      #pragma unroll
      for (int n = 0; n < 4; ++n) {
        float p = __expf((s_all[tile][n][r] - tm) * 0.125f);
        s_all[tile][n][r] = p;
        rs += p;
      }
    #pragma unroll
    for (int m = 1; m < 16; m <<= 1) rs += __shfl_xor(rs, m, 64);
    mrow[r] = tm; lrow[r] = rs;
  }

  // phase 3: PV over NT tiles
  f32x4 acc_o[4] = {};
  #pragma unroll
  for (int tile = 0; tile < NT; ++tile) {
    const unsigned short* Vsc = (tile & 1) ? KV1 : KV0;
    if (tile < NT - 1) writeV((tile + 1) & 1);
    if (tile < NT - 2) loadV(tile + 2);
    #pragma unroll
    for (int n = 0; n < 4; ++n)
      #pragma unroll
      for (int r = 0; r < 4; ++r)
        Ps[(w * 16 + g * 4 + r) * 72 + n * 16 + li] = f2b_rne(s_all[tile][n][r]);
    #pragma unroll
    for (int kk = 0; kk < 2; ++kk) {
      bf16x8 ap = *reinterpret_cast<const bf16x8*>(&Ps[(w * 16 + li) * 72 + kk * 32 + g * 8]);
      #pragma unroll
      for (int n = 0; n < 4; ++n) {
        bf16x8 bv = *reinterpret_cast<const bf16x8*>(&Vsc[(n * 16 + li) * 72 + kk * 32 + g * 8]);
        acc_o[n] = __builtin_amdgcn_mfma_f32_16x16x32_bf16(ap, bv, acc_o[n], 0, 0, 0);
      }
    }
    __syncthreads();
  }

  size_t rowbase = (size_t)slot * 1024;
  #pragma unroll
  for (int r = 0; r < 4; ++r) {
    int qr = q0 + w * 16 + g * 4 + r;
    #pragma unroll
    for (int n = 0; n < 4; ++n)
      pout[(rowbase + qr) * 64 + n * 16 + li] = acc_o[n][r];
    if (li == 0) {
      pml[(rowbase + qr) * 2 + 0] = mrow[r];
      pml[(rowbase + qr) * 2 + 1] = lrow[r];
    }
  }
}

// ---------------- 64x64 GEMM device body: BK=128, global_load_lds + 16-slot swizzle --
template <int HAS_BIAS, int BF16_OUT>
__device__ __forceinline__ void dev_gemm64(
    char* smem,
    const unsigned short* __restrict__ A, const unsigned short* __restrict__ B,
    void* __restrict__ Cv, const float* __restrict__ bias,
    unsigned short* __restrict__ vtp,
    int bx, int by, int K, int lda, int ldb, int ldc) {
  unsigned short* As = (unsigned short*)smem;     // [64][128]
  unsigned short* Bs = As + 64 * 128;
  int t = threadIdx.x, lane = t & 63, w = t >> 6;
  int wr = w >> 1, wc = w & 1;
  int g = lane >> 4, li = lane & 15;
  int mb = by * 64, nb = bx * 64;
  int rstg = t >> 4;            // 0..15
  int cs = t & 15;              // col16 slot
  f32x4 acc[2][2] = {};
  for (int kb = 0; kb < K; kb += 128) {
    __syncthreads();
    #pragma unroll
    for (int i = 0; i < 4; ++i) {
      int row = i * 16 + rstg;
      int csw = ((cs ^ (row & 7)) * 8);
      __builtin_amdgcn_global_load_lds(
          (const __attribute__((address_space(1))) unsigned int*)(A + (size_t)(mb + row) * lda + kb + csw),
          (__attribute__((address_space(3))) unsigned int*)(As + row * 128 + cs * 8), 16, 0, 0);
      __builtin_amdgcn_global_load_lds(
          (const __attribute__((address_space(1))) unsigned int*)(B + (size_t)(nb + row) * ldb + kb + csw),
          (__attribute__((address_space(3))) unsigned int*)(Bs + row * 128 + cs * 8), 16, 0, 0);
    }
    __syncthreads();
    #pragma unroll
    for (int kk = 0; kk < 4; ++kk) {
      bf16x8 af[2], bfr[2];
      #pragma unroll
      for (int m = 0; m < 2; ++m) {
        int r = wr * 32 + m * 16 + li;
        int cb = kk * 4 + g;
        af[m] = *reinterpret_cast<const bf16x8*>(&As[r * 128 + ((cb ^ (r & 7)) * 8)]);
      }
      #pragma unroll
      for (int n = 0; n < 2; ++n) {
        int r = wc * 32 + n * 16 + li;
        int cb = kk * 4 + g;
        bfr[n] = *reinterpret_cast<const bf16x8*>(&Bs[r * 128 + ((cb ^ (r & 7)) * 8)]);
      }
      #pragma unroll
      for (int m = 0; m < 2; ++m)
        #pragma unroll
        for (int n = 0; n < 2; ++n)
          acc[m][n] = __builtin_amdgcn_mfma_f32_16x16x32_bf16(af[m], bfr[n], acc[m][n], 0, 0, 0);
    }
  }
  if (vtp != nullptr && nb >= 1792) {
    #pragma unroll
    for (int m = 0; m < 2; ++m) {
      int row0 = mb + wr * 32 + m * 16 + g * 4;
      #pragma unroll
      for (int n = 0; n < 2; ++n) {
        int colrel = nb - 1792 + wc * 32 + n * 16 + li;
        #pragma unroll
        for (int r = 0; r < 4; ++r)
          vtp[(size_t)colrel * 1024 + row0 + r] = f2b_rne(acc[m][n][r]);
      }
    }
    return;
  }
  #pragma unroll
  for (int m = 0; m < 2; ++m) {
    int row0 = mb + wr * 32 + m * 16 + g * 4;
    #pragma unroll
    for (int n = 0; n < 2; ++n) {
      int col = nb + wc * 32 + n * 16 + li;
      float bval = HAS_BIAS ? bias[col] : 0.0f;
      #pragma unroll
      for (int r = 0; r < 4; ++r) {
        size_t idx = (size_t)(row0 + r) * ldc + col;
        if (BF16_OUT) ((unsigned short*)Cv)[idx] = f2b_rne(acc[m][n][r] + bval);
        else          ((float*)Cv)[idx] = acc[m][n][r] + bval;
      }
    }
  }
}

// ---------------- fused: quantum attention (blocks 0..255) + QKV GEMM (256..927) -----
__global__ __launch_bounds__(256) void k_qkvq(
    const unsigned short* __restrict__ x_bf, const unsigned short* __restrict__ wqkv,
    unsigned short* __restrict__ qkv, unsigned short* __restrict__ vt,
    const unsigned short* __restrict__ qcs, const unsigned short* __restrict__ kcs,
    const unsigned short* __restrict__ xt,
    float* __restrict__ pout, float* __restrict__ pml) {
  __shared__ __align__(16) char smem[44032];   // max(quantum 44032, gemm 32768)
  int bid = blockIdx.x;
  if (bid < 256) {
    int qt = bid & 15, h = (bid >> 4) & 1, split = bid >> 5;   // 8 splits, NT=2
    dev_fattn2<128, 2>(smem, qcs + (size_t)h * SEQ * 128, 128,
                       kcs + (size_t)h * SEQ * 128, 128,
                       xt + (size_t)h * 65536,
                       qt * 64, split * 128, h * 8 + split, pout, pml);
  } else {
    int gb = bid - 256;
    int swz = (gb & 7) * 84 + (gb >> 3);       // XCD-chunked (672 % 8 == 0)
    int by = swz / 42, bx = swz % 42;
    dev_gemm64<0, 1>(smem, x_bf, wqkv, qkv, nullptr, vt, bx, by, DIMX, DIMX, DIMX, QKVN);
  }
}

// ---------------- trad attention (896 blocks, XCD-chunked) ----------------
__global__ __launch_bounds__(256) void k_tattn(
    const unsigned short* __restrict__ qkv, const unsigned short* __restrict__ vt,
    float* __restrict__ pout, float* __restrict__ pml) {
  __shared__ __align__(16) char smem[27648];
  int bid = blockIdx.x;
  int swz = (bid & 7) * 112 + (bid >> 3);      // 896 % 8 == 0
  int qt = swz & 15, hs = swz >> 4;
  int h = hs % 14, split = hs / 14;            // 4 splits, NT=4
  dev_fattn2<64, 4>(smem, qkv + h * 64, QKVN,
                    qkv + 896 + h * 64, QKVN,
                    vt + (size_t)h * 65536,
                    qt * 64, split * 256, 16 + h * 4 + split, pout, pml);
}

// ---------------- merge kv-split partials -> concat bf16 ----------------
__global__ __launch_bounds__(256) void k_fmerge(
    const float* __restrict__ pout, const float* __restrict__ pml,
    unsigned short* __restrict__ concat) {
  int rq = blockIdx.x * 4 + (threadIdx.x >> 6);
  int lh = rq >> 10, q = rq & 1023;
  int d = threadIdx.x & 63;
  int s0 = (lh < 2) ? lh * 8 : 16 + (lh - 2) * 4;
  int ns = (lh < 2) ? 8 : 4;
  float m_s[8], l_s[8];
  float M = -1e30f;
  #pragma unroll
  for (int s = 0; s < 8; ++s) {
    if (s < ns) {
      size_t rb = (size_t)(s0 + s) * 1024 + q;
      m_s[s] = pml[rb * 2 + 0];
      l_s[s] = pml[rb * 2 + 1];
      M = fmaxf(M, m_s[s]);
    }
  }
  float num = 0.f, den = 0.f;
  #pragma unroll
  for (int s = 0; s < 8; ++s) {
    if (s < ns) {
      float wgt = __expf((m_s[s] - M) * 0.125f);
      num += wgt * pout[((size_t)(s0 + s) * 1024 + q) * 64 + d];
      den += wgt * l_s[s];
    }
  }
  concat[(size_t)q * DIMX + lh * 64 + d] = f2b_rne(num / den);
}

// ---------------- output projection (256 blocks, XCD-chunked) ----------------
__global__ __launch_bounds__(256) void k_oproj(
    const unsigned short* __restrict__ concat, const unsigned short* __restrict__ wo_bf,
    float* __restrict__ out, const float* __restrict__ bo) {
  __shared__ __align__(16) char smem[32768];
  int bid = blockIdx.x;
  int swz = (bid & 7) * 32 + (bid >> 3);       // 256 % 8 == 0
  int by = swz / 16, bx = swz % 16;
  dev_gemm64<1, 0>(smem, concat, wo_bf, out, bo, nullptr, bx, by, DIMX, DIMX, DIMX, DIMX);
}

extern "C" void kernel_launch(void* const* d_in, const int* in_sizes, int n_in,
                              void* d_out, int out_size, void* d_ws, size_t ws_size,
                              hipStream_t stream) {
  const float* x      = (const float*)d_in[0];
  const float* qsW    = (const float*)d_in[1];
  const float* qsb    = (const float*)d_in[2];
  const float* lng    = (const float*)d_in[3];
  const float* lnb    = (const float*)d_in[4];
  const float* qfreq  = (const float*)d_in[5];
  const float* qshift = (const float*)d_in[6];
  const float* Wq     = (const float*)d_in[7];
  const float* Wk     = (const float*)d_in[8];
  const float* Wv     = (const float*)d_in[9];
  const float* Wo     = (const float*)d_in[10];
  const float* bo     = (const float*)d_in[11];
  float* out = (float*)d_out;

  char* ws = (char*)d_ws;
  size_t off = 0;
  auto alloc = [&](size_t bytes) { char* p = ws + off; off += (bytes + 255) & ~(size_t)255; return p; };
  unsigned short* x_bf      = (unsigned short*)alloc((size_t)SEQ * DIMX * 2);
  unsigned short* wqkv_bf   = (unsigned short*)alloc((size_t)QKVN * DIMX * 2);
  unsigned short* wo_bf     = (unsigned short*)alloc((size_t)DIMX * DIMX * 2);
  unsigned short* concat_bf = (unsigned short*)alloc((size_t)SEQ * DIMX * 2);
  unsigned short* qkv_bf    = (unsigned short*)alloc((size_t)SEQ * QKVN * 2);
  unsigned short* qcs       = (unsigned short*)alloc((size_t)QH * SEQ * 128 * 2);
  unsigned short* kcs       = (unsigned short*)alloc((size_t)QH * SEQ * 128 * 2);
  unsigned short* vt        = (unsigned short*)alloc((size_t)TH * HD * SEQ * 2);
  unsigned short* xt        = (unsigned short*)alloc((size_t)QH * HD * SEQ * 2);
  float*          pout      = (float*)alloc((size_t)72 * SEQ * 64 * 4);
  float*          pml       = (float*)alloc((size_t)72 * SEQ * 2 * 4);

  // 1. prep
  k_prep<<<NB_F2B + NB_QPREP + NB_XT, 256, 0, stream>>>(
      x, qsW, qsb, lng, lnb, qfreq, qshift, Wq, Wk, Wv, Wo,
      x_bf, wqkv_bf, wo_bf, qcs, kcs, xt);

  // 2. quantum attention + QKV projection fused (V tiles straight to vt transposed)
  k_qkvq<<<928, 256, 0, stream>>>(x_bf, wqkv_bf, qkv_bf, vt, qcs, kcs, xt, pout, pml);

  // 3. trad attention
  k_tattn<<<896, 256, 0, stream>>>(qkv_bf, vt, pout, pml);

  // 4. merge
  k_fmerge<<<16 * SEQ / 4, 256, 0, stream>>>(pout, pml, concat_bf);

  // 5. output projection + bias
  k_oproj<<<256, 256, 0, stream>>>(concat_bf, wo_bf, out, bo);
}